// Round 9
// baseline (478.737 us; speedup 1.0000x reference)
//
#include <hip/hip_runtime.h>
#include <hip/hip_bf16.h>
#include <math.h>

typedef unsigned short u16;
typedef unsigned long long u64;
#define DEV static __device__ __forceinline__

// ---------------- problem constants ----------------
constexpr int Bz = 2, N0 = 4096, N1 = 1024, N2 = 256, KNN = 20, NA = 12;
constexpr int C0 = 32, C1 = 64, C2 = 128, C3 = 256, C4 = 512;
constexpr int BNG = 32;  // batchnorm atomic groups

// ---------------- workspace layout ----------------
constexpr size_t OFF_V0F   = 0;                       // Bz*N0 float4 (w = |p|^2)
constexpr size_t OFF_V1F   = 32768;
constexpr size_t OFF_V2F   = 40960;
constexpr size_t OFF_K0F   = 43008;                   // 1152
constexpr size_t OFF_DIRS  = 44160;                   // 144
constexpr size_t OFF_WC    = 44304;                   // 174080
constexpr size_t OFF_WS    = 218384;                  // 174080
constexpr size_t OFF_BC    = 392464;                  // 960
constexpr size_t OFF_BN    = 393424;                  // 896
constexpr size_t OFF_FLAG  = 394832;                  // 16 (unused now)
constexpr size_t OFF_IDX0  = 394848;                  // 163840 ints
constexpr size_t OFF_IDX1  = 558688;                  // 40960
constexpr size_t OFF_IDX2  = 599648;                  // 10240
constexpr size_t OFF_PART  = 609888;                  // 28672 floats
constexpr size_t PART_SZ   = 28672;
constexpr size_t OFF_HALF  = OFF_PART + PART_SZ;      // u16 arena base (float offset)

constexpr size_t HA = 0;                              // fm0/fm2
constexpr size_t HB = 3145728;                        // fm1/fm3 ; layer4: fc4 as f32
constexpr size_t HG = 9437184;                        // g1..g4
constexpr size_t HP = HG + 3145728;                   // fmp1/fmp2 (upper half of G)

// output element offsets (float32)
constexpr size_t OUT0 = 0;
constexpr size_t OUT1 = OUT0 + (size_t)Bz*N0*C0;
constexpr size_t OUT2 = OUT1 + (size_t)Bz*N0*C1;
constexpr size_t OUT3 = OUT2 + (size_t)Bz*N1*C2;
constexpr size_t OUT4 = OUT3 + (size_t)Bz*N1*C3;

DEV float b2f(u16 v) { return __uint_as_float(((unsigned int)v) << 16); }
DEV u16 f2b(float f) {
  unsigned int u = __float_as_uint(f);
  unsigned int lsb = (u >> 16) & 1u;
  return (u16)((u + 0x7fffu + lsb) >> 16);
}
DEV unsigned packb(float a, float b) {
  return (unsigned)f2b(a) | ((unsigned)f2b(b) << 16);
}

DEV u64 shflx64(u64 v, int m) {
  int lo = __shfl_xor((int)(unsigned)v, m, 64);
  int hi = __shfl_xor((int)(unsigned)(v >> 32), m, 64);
  return ((u64)(unsigned)hi << 32) | (unsigned)lo;
}
DEV int mbcnt64(u64 m) {
  return __builtin_amdgcn_mbcnt_hi((unsigned)(m >> 32),
         __builtin_amdgcn_mbcnt_lo((unsigned)m, 0));
}

DEV void st12(float* dst, const float* v) {
  float4 a{v[0],v[1],v[2],v[3]}, b{v[4],v[5],v[6],v[7]}, c{v[8],v[9],v[10],v[11]};
  ((float4*)dst)[0] = a; ((float4*)dst)[1] = b; ((float4*)dst)[2] = c;
}
DEV void st12(u16* dst, const float* v) {
  uint2 a{packb(v[0],v[1]), packb(v[2],v[3])};
  uint2 b{packb(v[4],v[5]), packb(v[6],v[7])};
  uint2 c{packb(v[8],v[9]), packb(v[10],v[11])};
  ((uint2*)dst)[0] = a; ((uint2*)dst)[1] = b; ((uint2*)dst)[2] = c;
}

// ---------------- convert all inputs -> f32 (self dtype-detect, zero partials) ----------------
struct InPtrs { const void* p[24]; };

__global__ void eq_convert_all(InPtrs in, float* ws) {
  __shared__ int sflag;
  {
    const u16* v = (const u16*)in.p[0];
    if (threadIdx.x < 64) {
      int bad = 0;
      #pragma unroll
      for (int j = 0; j < 4; ++j) {
        unsigned u = v[threadIdx.x*4 + j];
        int ex = (u >> 7) & 0xFF;
        bad += (((u & 0x7FFFu) != 0u) && (ex < 64 || ex > 191)) ? 1 : 0;
      }
      int tot = bad;
      #pragma unroll
      for (int s = 32; s > 0; s >>= 1) tot += __shfl_xor(tot, s, 64);
      if (threadIdx.x == 0) sflag = (tot >= 8) ? 1 : 0;   // 1 => inputs are f32
    }
    __syncthreads();
  }
  int f32mode = sflag;
  int t = blockIdx.x * blockDim.x + threadIdx.x;
  if (t < Bz*N0) {      // one thread per point; w = |p|^2
    float x, y, z;
    if (f32mode) { const float* v = (const float*)in.p[0]; x=v[t*3]; y=v[t*3+1]; z=v[t*3+2]; }
    else { const u16* v = (const u16*)in.p[0]; x=b2f(v[t*3]); y=b2f(v[t*3+1]); z=b2f(v[t*3+2]); }
    float4 o; o.x=x; o.y=y; o.z=z; o.w=(x*x + y*y) + z*z;
    ((float4*)(ws + OFF_V0F))[t] = o;
    int b = t / N0, i = t % N0;
    if ((i & 3) == 0)  ((float4*)(ws + OFF_V1F))[b*N1 + (i >> 2)] = o;
    if ((i & 15) == 0) ((float4*)(ws + OFF_V2F))[b*N2 + (i >> 4)] = o;
    return;
  }
  int r = t - Bz*N0;
  if (r >= 351312) {    // tail range zeroes bn partials
    int z = r - 351312;
    if (z < (int)PART_SZ) ws[OFF_PART + z] = 0.f;
    return;
  }
  const int cnt[23] = {1152, 36,2048,64,2048, 36,8192,128,8192,
                       36,32768,256,32768, 36,131072,512,131072,
                       64,64,128,128,256,256};
  const size_t off[23] = {OFF_K0F,
    OFF_DIRS+0,   OFF_WC+0,     OFF_BC+0,   OFF_WS+0,
    OFF_DIRS+36,  OFF_WC+2048,  OFF_BC+64,  OFF_WS+2048,
    OFF_DIRS+72,  OFF_WC+10240, OFF_BC+192, OFF_WS+10240,
    OFF_DIRS+108, OFF_WC+43008, OFF_BC+448, OFF_WS+43008,
    OFF_BN+0, OFF_BN+64, OFF_BN+128, OFF_BN+256, OFF_BN+384, OFF_BN+640};
  for (int i = 0; i < 23; ++i) {
    if (r < cnt[i]) {
      float val = f32mode ? ((const float*)in.p[i+1])[r] : b2f(((const u16*)in.p[i+1])[r]);
      ws[off[i] + r] = val;
      return;
    }
    r -= cnt[i];
  }
}

// ---------------- KNN v9: v8 main pass + fast exact re-enumeration fallback ----------------
// exact monotone-uint squared distance; fmaf-pinned (identical in all passes)
DEV unsigned cand_ud(const float4 vq, const float4 vc) {
  float dt = fmaf(vq.x, vc.x, fmaf(vq.y, vc.y, vq.z*vc.z));
  float d  = fmaf(-2.0f, dt, vq.w + vc.w);
  unsigned u = __float_as_uint(d);
  return u ^ ((unsigned)(((int)u) >> 31) | 0x80000000u);
}

// exact sorted-insert into network A/B (round-0 proven cndmask network)
#define INSA(u,c) do { bool lt1=(u)<dA1, lt2=(u)<dA2, lt3=(u)<dA3, lt4=(u)<dA4; \
  dA4=lt3?dA3:(lt4?(u):dA4); iA4=lt3?iA3:(lt4?(c):iA4); \
  dA3=lt2?dA2:(lt3?(u):dA3); iA3=lt2?iA2:(lt3?(c):iA3); \
  dA2=lt1?dA1:(lt2?(u):dA2); iA2=lt1?iA1:(lt2?(c):iA2); \
  dA1=lt1?(u):dA1;           iA1=lt1?(c):iA1; } while(0)
#define INSB(u,c) do { bool lt1=(u)<dB1, lt2=(u)<dB2, lt3=(u)<dB3, lt4=(u)<dB4; \
  dB4=lt3?dB3:(lt4?(u):dB4); iB4=lt3?iB3:(lt4?(c):iB4); \
  dB3=lt2?dB2:(lt3?(u):dB3); iB3=lt2?iB2:(lt3?(c):iB3); \
  dB2=lt1?dB1:(lt2?(u):dB2); iB2=lt1?iB1:(lt2?(c):iB2); \
  dB1=lt1?(u):dB1;           iB1=lt1?(c):iB1; } while(0)

// ballot-compact one candidate (ud,cc) with ud <= p into selw (128 slots)
#define CMP1(uu,cc) do { bool sel=(uu)<=p; u64 m=__ballot(sel); \
  int pos = base2 + mbcnt64(m); \
  if (sel && pos < 128) selw[pos] = ((u64)(uu) << 32) | (unsigned)(cc); \
  base2 += __popcll(m); } while(0)

template<int NPTS>
DEV void knn_body(int blk, const float4* __restrict__ vf, int* __restrict__ idx_out,
                  char* smem) {
  constexpr int CPL = NPTS/64;       // candidates per lane
  constexpr int HC  = CPL/2;         // candidates per network
  int wave = threadIdx.x >> 6, lane = threadIdx.x & 63;
  u64* selw = (u64*)smem + wave*128;
  int* extrw = (int*)(smem + 4*128*8) + wave*24;
  int qid = blk*4 + wave;
  int b = qid / NPTS, q = qid % NPTS;
  const float4* vb = vf + (size_t)b*NPTS;
  float4 vq = vb[q];

  // dual exact top-4 (d,i) networks: A = even candidates of each batch, B = odd.
  unsigned dA1=~0u,dA2=~0u,dA3=~0u,dA4=~0u; int iA1=0,iA2=0,iA3=0,iA4=0;
  unsigned dB1=~0u,dB2=~0u,dB3=~0u,dB4=~0u; int iB1=0,iB2=0,iB3=0,iB4=0;

  if (CPL >= 8) {
    // MLP-8: 8 independent loads issued back-to-back into NAMED regs, then 8 updates.
    for (int jb = 0; jb < CPL; jb += 8) {
      int base = jb*64 + lane;
      float4 c0 = vb[base];
      float4 c1 = vb[base + 64];
      float4 c2 = vb[base + 128];
      float4 c3 = vb[base + 192];
      float4 c4 = vb[base + 256];
      float4 c5 = vb[base + 320];
      float4 c6 = vb[base + 384];
      float4 c7 = vb[base + 448];
      unsigned u0 = cand_ud(vq, c0);
      unsigned u1 = cand_ud(vq, c1);
      unsigned u2 = cand_ud(vq, c2);
      unsigned u3 = cand_ud(vq, c3);
      unsigned u4 = cand_ud(vq, c4);
      unsigned u5 = cand_ud(vq, c5);
      unsigned u6 = cand_ud(vq, c6);
      unsigned u7 = cand_ud(vq, c7);
      INSA(u0, base);       INSB(u1, base + 64);
      INSA(u2, base + 128); INSB(u3, base + 192);
      INSA(u4, base + 256); INSB(u5, base + 320);
      INSA(u6, base + 384); INSB(u7, base + 448);
    }
  } else {
    // CPL == 4 (N2): single batch of 4 (networks hold ALL candidates => no fallback)
    int base = lane;
    float4 c0 = vb[base];
    float4 c1 = vb[base + 64];
    float4 c2 = vb[base + 128];
    float4 c3 = vb[base + 192];
    unsigned u0 = cand_ud(vq, c0);
    unsigned u1 = cand_ud(vq, c1);
    unsigned u2 = cand_ud(vq, c2);
    unsigned u3 = cand_ud(vq, c3);
    INSA(u0, base);       INSB(u1, base + 64);
    INSA(u2, base + 128); INSB(u3, base + 192);
  }

  // radix-select (KNN+1)-th smallest ud over the wave's kept 8-reg survivor set.
  unsigned p = 0;
  for (int bit = 31; bit >= 0; --bit) {
    unsigned T = p | (1u << bit);
    int cnt = __popcll(__ballot(dA1 < T)) + __popcll(__ballot(dA2 < T))
            + __popcll(__ballot(dA3 < T)) + __popcll(__ballot(dA4 < T))
            + __popcll(__ballot(dB1 < T)) + __popcll(__ballot(dB2 < T))
            + __popcll(__ballot(dB3 < T)) + __popcll(__ballot(dB4 < T));
    if (cnt < KNN+1) p = T;
  }
  size_t obase = (size_t)qid*KNN;
  // a network whose kept 4th-best is within threshold may have dropped a winner
  bool need_fb = (HC > 4) &&
                 ((__ballot(dA4 <= p) | __ballot(dB4 <= p)) != 0ULL);

  if (!need_fb) {
    bool pA1=dA1<=p, pA2=dA2<=p, pA3=dA3<=p, pA4=dA4<=p;
    bool pB1=dB1<=p, pB2=dB2<=p, pB3=dB3<=p, pB4=dB4<=p;
    u64 m1=__ballot(pA1), m2=__ballot(pA2), m3=__ballot(pA3), m4=__ballot(pA4);
    u64 m5=__ballot(pB1), m6=__ballot(pB2), m7=__ballot(pB3), m8=__ballot(pB4);
    int c1=__popcll(m1), c2=__popcll(m2), c3=__popcll(m3), c4=__popcll(m4);
    int c5=__popcll(m5), c6=__popcll(m6), c7=__popcll(m7), c8=__popcll(m8);
    int S = ((c1+c2)+(c3+c4)) + ((c5+c6)+(c7+c8));
    if (S > 127) need_fb = true;
    else {
      int o1=c1, o2=o1+c2, o3=o2+c3, o4=o3+c4, o5=o4+c5, o6=o5+c6, o7=o6+c7;
      if (pA1) selw[mbcnt64(m1)]      = ((u64)dA1 << 32) | (unsigned)iA1;
      if (pA2) selw[o1 + mbcnt64(m2)] = ((u64)dA2 << 32) | (unsigned)iA2;
      if (pA3) selw[o2 + mbcnt64(m3)] = ((u64)dA3 << 32) | (unsigned)iA3;
      if (pA4) selw[o3 + mbcnt64(m4)] = ((u64)dA4 << 32) | (unsigned)iA4;
      if (pB1) selw[o4 + mbcnt64(m5)] = ((u64)dB1 << 32) | (unsigned)iB1;
      if (pB2) selw[o5 + mbcnt64(m6)] = ((u64)dB2 << 32) | (unsigned)iB2;
      if (pB3) selw[o6 + mbcnt64(m7)] = ((u64)dB3 << 32) | (unsigned)iB3;
      if (pB4) selw[o7 + mbcnt64(m8)] = ((u64)dB4 << 32) | (unsigned)iB4;
      for (int sl = lane; sl < S; sl += 64) {
        u64 mykey = selw[sl];
        int rank = 0;
        for (int j2 = 0; j2 < S; ++j2) rank += (selw[j2] < mykey) ? 1 : 0;
        if (rank >= 1 && rank <= KNN)     // rank 0 = self
          idx_out[obase + rank - 1] = (int)(unsigned)(mykey & 0xFFFFFFFFu);
      }
    }
  }
  if (need_fb && CPL >= 8) {
    // ---- fast exact fallback: full re-stream, compact ALL ud <= p (superset of
    // true top-21) into 128-slot selw, then rank-select. Chain-free, no rescans.
    int base2 = 0;
    for (int jb = 0; jb < CPL; jb += 8) {
      int bidx = jb*64 + lane;
      float4 c0 = vb[bidx];
      float4 c1 = vb[bidx + 64];
      float4 c2 = vb[bidx + 128];
      float4 c3 = vb[bidx + 192];
      float4 c4 = vb[bidx + 256];
      float4 c5 = vb[bidx + 320];
      float4 c6 = vb[bidx + 384];
      float4 c7 = vb[bidx + 448];
      unsigned u0 = cand_ud(vq, c0);
      unsigned u1 = cand_ud(vq, c1);
      unsigned u2 = cand_ud(vq, c2);
      unsigned u3 = cand_ud(vq, c3);
      unsigned u4 = cand_ud(vq, c4);
      unsigned u5 = cand_ud(vq, c5);
      unsigned u6 = cand_ud(vq, c6);
      unsigned u7 = cand_ud(vq, c7);
      CMP1(u0, bidx);       CMP1(u1, bidx + 64);
      CMP1(u2, bidx + 128); CMP1(u3, bidx + 192);
      CMP1(u4, bidx + 256); CMP1(u5, bidx + 320);
      CMP1(u6, bidx + 384); CMP1(u7, bidx + 448);
    }
    if (base2 <= 127) {
      int S = base2;
      for (int sl = lane; sl < S; sl += 64) {
        u64 mykey = selw[sl];
        int rank = 0;
        for (int j2 = 0; j2 < S; ++j2) rank += (selw[j2] < mykey) ? 1 : 0;
        if (rank >= 1 && rank <= KNN)
          idx_out[obase + rank - 1] = (int)(unsigned)(mykey & 0xFFFFFFFFu);
      }
    } else {
      // ---- ultimate guard (degenerate ties, ~never): proven serial extraction
      const u64 KINF = ~0ULL;
      u64 K1=KINF, K2=KINF, K3=KINF, K4=KINF;
      for (int j = 0; j < CPL; ++j) {
        int c = j*64 + lane;
        u64 k = ((u64)cand_ud(vq, vb[c]) << 32) | (unsigned)c;
        bool lt1 = k < K1, lt2 = k < K2, lt3 = k < K3, lt4 = k < K4;
        K4 = lt3 ? K3 : (lt4 ? k : K4);
        K3 = lt2 ? K2 : (lt3 ? k : K3);
        K2 = lt1 ? K1 : (lt2 ? k : K2);
        K1 = lt1 ? k  : K1;
      }
      for (int r = 0; r < KNN+1; ++r) {
        u64 g = K1;
        #pragma unroll
        for (int s = 32; s; s >>= 1) { u64 o = shflx64(g, s); g = (o < g) ? o : g; }
        int gidx = (int)(unsigned)(g & 0xFFFFFFFFu);
        if (lane == 0) {
          extrw[r] = gidx;
          if (r > 0) idx_out[obase + r - 1] = gidx;
        }
        if (r < KNN && lane == (gidx & 63)) {
          K1 = K2; K2 = K3; K3 = K4; K4 = KINF;
          if (K1 == KINF) {
            for (int j = 0; j < CPL; ++j) {
              int c = j*64 + lane;
              u64 k = ((u64)cand_ud(vq, vb[c]) << 32) | (unsigned)c;
              bool ex = false;
              for (int e = 0; e <= r; ++e) ex |= (extrw[e] == c);
              if (!ex) {
                bool lt1 = k < K1, lt2 = k < K2, lt3 = k < K3, lt4 = k < K4;
                K4 = lt3 ? K3 : (lt4 ? k : K4);
                K3 = lt2 ? K2 : (lt3 ? k : K3);
                K2 = lt1 ? K1 : (lt2 ? k : K2);
                K1 = lt1 ? k  : K1;
              }
            }
          }
        }
      }
    }
  }
}

// ---------------- fused KNN: all 3 levels in one dispatch ----------------
__global__ __launch_bounds__(256) void eq_knn_all(
    const float4* __restrict__ v0, int* __restrict__ i0,
    const float4* __restrict__ v1, int* __restrict__ i1,
    const float4* __restrict__ v2, int* __restrict__ i2) {
  __shared__ __align__(16) char smem[4*128*8 + 4*24*4];
  int blk = blockIdx.x;
  constexpr int NB0 = Bz*N0/4, NB1 = Bz*N1/4;
  if (blk < NB0)            knn_body<N0>(blk, v0, i0, smem);
  else if (blk < NB0+NB1)   knn_body<N1>(blk - NB0, v1, i1, smem);
  else                      knn_body<N2>(blk - NB0 - NB1, v2, i2, smem);
}

// ---------------- conv_surface + relu + fea_of(fm0), vectorized stores ----------------
__global__ __launch_bounds__(128) void eq_conv_surface(
    const float4* __restrict__ v0f, const int* __restrict__ idx0,
    const float* __restrict__ K0f, u16* __restrict__ fm0, float* __restrict__ out0) {
  int bq = blockIdx.x;          // b*N0 + q
  int b = bq >> 12;
  __shared__ float dk[KNN][3];
  __shared__ float row[C0*NA];
  int tid = threadIdx.x;
  if (tid < KNN) {
    int m = idx0[(size_t)bq*KNN + tid];
    float4 vq = v0f[bq];
    float4 vm = v0f[(size_t)b*N0 + m];
    float dx = vm.x - vq.x, dy = vm.y - vq.y, dz = vm.z - vq.z;
    float nrm = sqrtf((dx*dx + dy*dy) + dz*dz) + 1e-8f;
    dk[tid][0] = dx/nrm; dk[tid][1] = dy/nrm; dk[tid][2] = dz/nrm;
  }
  __syncthreads();
  for (int t4 = tid; t4 < C0*NA/4; t4 += 128) {
    const float* kd = K0f + (size_t)t4*12;
    float4 k0 = *(const float4*)(kd);
    float4 k1 = *(const float4*)(kd + 4);
    float4 k2 = *(const float4*)(kd + 8);
    float m0=0.f, m1=0.f, m2=0.f, m3=0.f;   // relu then max => >= 0
    #pragma unroll
    for (int k = 0; k < KNN; ++k) {
      float dx = dk[k][0], dy = dk[k][1], dz = dk[k][2];
      m0 = fmaxf(m0, (dx*k0.x + dy*k0.y) + dz*k0.z);
      m1 = fmaxf(m1, (dx*k0.w + dy*k1.x) + dz*k1.y);
      m2 = fmaxf(m2, (dx*k1.z + dy*k1.w) + dz*k2.x);
      m3 = fmaxf(m3, (dx*k2.y + dy*k2.z) + dz*k2.w);
    }
    uint2 r; r.x = packb(m0, m1); r.y = packb(m2, m3);
    ((uint2*)fm0)[(size_t)bq*(C0*NA/4) + t4] = r;
    row[4*t4+0] = m0; row[4*t4+1] = m1; row[4*t4+2] = m2; row[4*t4+3] = m3;
  }
  __syncthreads();
  if (tid < C0) {
    float m = row[tid*NA];
    #pragma unroll
    for (int a = 1; a < NA; ++a) m = fmaxf(m, row[tid*NA + a]);
    out0[(size_t)bq*C0 + tid] = m;
  }
}

// ---------------- linear v5: 4 outputs/thread, vectorized staging ----------------
// one matrix per block (blockIdx&1); FMA order over c preserved => bit-identical
template<int CI, int CO, typename TO>
__global__ __launch_bounds__(256) void eq_linear4(
    const u16* __restrict__ in, const float* __restrict__ Wc,
    const float* __restrict__ Ws, const float* __restrict__ bias,
    TO* __restrict__ fc, u16* __restrict__ g) {
  constexpr int PPB = 1024 / CO;        // points per block (256 thr x 4 outs)
  constexpr int RS = CI*NA + 4;
  __shared__ float lds[PPB*RS];
  int tid = threadIdx.x;
  int mat = blockIdx.x & 1;
  int pt0 = (blockIdx.x >> 1) * PPB;
  constexpr int E = PPB*CI*NA;          // CI*NA % 4 == 0 => quads never straddle pts
  for (int t = tid; t < E/4; t += 256) {
    int e = 4*t;
    int pt = e / (CI*NA), r = e % (CI*NA);
    uint2 v = *(const uint2*)(in + (size_t)(pt0+pt)*CI*NA + r);
    float* d = &lds[pt*RS + r];
    d[0] = b2f((u16)v.x); d[1] = b2f((u16)(v.x >> 16));
    d[2] = b2f((u16)v.y); d[3] = b2f((u16)(v.y >> 16));
  }
  __syncthreads();
  constexpr int TPP = CO/4;             // threads per point
  int oq = tid % TPP, pt = tid / TPP;
  int o0 = oq*4;
  const float* W = mat ? Ws : Wc;
  const float* row = lds + pt*RS;
  float a0[NA], a1[NA], a2[NA], a3[NA];
  #pragma unroll
  for (int a = 0; a < NA; ++a) { a0[a]=0.f; a1[a]=0.f; a2[a]=0.f; a3[a]=0.f; }
  #pragma unroll 4
  for (int c = 0; c < CI; ++c) {
    float4 w4 = *(const float4*)(W + (size_t)c*CO + o0);
    float4 i0 = *(const float4*)(row + c*NA);
    float4 i1 = *(const float4*)(row + c*NA + 4);
    float4 i2 = *(const float4*)(row + c*NA + 8);
    float iv[NA] = {i0.x,i0.y,i0.z,i0.w, i1.x,i1.y,i1.z,i1.w, i2.x,i2.y,i2.z,i2.w};
    #pragma unroll
    for (int a = 0; a < NA; ++a) {
      a0[a] += iv[a]*w4.x; a1[a] += iv[a]*w4.y;
      a2[a] += iv[a]*w4.z; a3[a] += iv[a]*w4.w;
    }
  }
  size_t ptg = pt0 + pt;
  if (mat == 0) {
    float b0 = bias[o0], b1 = bias[o0+1], b2v = bias[o0+2], b3 = bias[o0+3];
    #pragma unroll
    for (int a = 0; a < NA; ++a) { a0[a] += b0; a1[a] += b1; a2[a] += b2v; a3[a] += b3; }
    st12(fc + ((size_t)ptg*CO + o0)*NA, a0);
    st12(fc + ((size_t)ptg*CO + o0 + 1)*NA, a1);
    st12(fc + ((size_t)ptg*CO + o0 + 2)*NA, a2);
    st12(fc + ((size_t)ptg*CO + o0 + 3)*NA, a3);
  } else {
    st12(g + ((size_t)ptg*CO + o0)*NA, a0);
    st12(g + ((size_t)ptg*CO + o0 + 1)*NA, a1);
    st12(g + ((size_t)ptg*CO + o0 + 2)*NA, a2);
    st12(g + ((size_t)ptg*CO + o0 + 3)*NA, a3);
  }
}

// ---------------- fsmax + fused BN partial stats (unroll 5, f4 th loads) ----------------
__global__ __launch_bounds__(256) void eq_fsmax(
    const u16* __restrict__ g, const float4* __restrict__ vf,
    const float* __restrict__ dirs, const int* __restrict__ idx,
    u16* __restrict__ out, float* __restrict__ part, int npts, int co) {
  int bq = blockIdx.x;
  int b = bq / npts;
  __shared__ float th[KNN*NA];
  __shared__ float dk[KNN][3];
  __shared__ int nb[KNN];
  __shared__ float sstat[2][C3];     // co <= 256
  int tid = threadIdx.x;
  if (tid < KNN) {
    int m = idx[(size_t)bq*KNN + tid];
    nb[tid] = m;
    float4 vq = vf[bq];
    float4 vm = vf[(size_t)b*npts + m];
    float dx = vm.x - vq.x, dy = vm.y - vq.y, dz = vm.z - vq.z;
    float nrm = sqrtf((dx*dx + dy*dy) + dz*dz) + 1e-8f;
    dk[tid][0] = dx/nrm; dk[tid][1] = dy/nrm; dk[tid][2] = dz/nrm;
  }
  sstat[0][tid] = 0.f; sstat[1][tid] = 0.f;
  __syncthreads();
  if (tid < KNN*NA) {
    int k = tid / NA, a = tid % NA;
    float s = (dk[k][0]*dirs[a*3] + dk[k][1]*dirs[a*3+1]) + dk[k][2]*dirs[a*3+2];
    th[tid] = fmaxf(s, 0.f);
  }
  __syncthreads();
  int quarter = co*NA/4;
  uint2* dst = (uint2*)(out + (size_t)bq*co*NA);
  const uint2* gb = (const uint2*)(g + (size_t)b*npts*co*NA);
  for (int t4 = tid; t4 < quarter; t4 += 256) {
    int a = (4*t4) % NA;          // 0, 4, or 8 — quad never straddles an o-row
    const float* tha = th + a;
    float m0=-3.0e38f, m1=-3.0e38f, m2=-3.0e38f, m3=-3.0e38f;
    #pragma unroll 5
    for (int k = 0; k < KNN; ++k) {
      uint2 pv = gb[(size_t)nb[k]*quarter + t4];
      float4 tv = *(const float4*)(tha + k*NA);   // 16B-aligned: a%4==0, 48|k*NA*4
      m0 = fmaxf(m0, tv.x*b2f((u16)(pv.x)));
      m1 = fmaxf(m1, tv.y*b2f((u16)(pv.x >> 16)));
      m2 = fmaxf(m2, tv.z*b2f((u16)(pv.y)));
      m3 = fmaxf(m3, tv.w*b2f((u16)(pv.y >> 16)));
    }
    uint2 d = dst[t4];
    float v0 = b2f((u16)d.x) + m0;
    float v1 = b2f((u16)(d.x >> 16)) + m1;
    float v2 = b2f((u16)d.y) + m2;
    float v3 = b2f((u16)(d.y >> 16)) + m3;
    uint2 r; r.x = packb(v0, v1); r.y = packb(v2, v3);
    dst[t4] = r;
    int ch = t4 / 3;              // NA/4 = 3 quads per channel
    atomicAdd(&sstat[0][ch], (v0 + v1) + (v2 + v3));
    atomicAdd(&sstat[1][ch], (v0*v0 + v1*v1) + (v2*v2 + v3*v3));
  }
  __syncthreads();
  if (tid < co) {
    float* pg = part + (size_t)(bq & (BNG-1))*2*co;
    atomicAdd(&pg[tid], sstat[0][tid]);
    atomicAdd(&pg[co + tid], sstat[1][tid]);
  }
}

// ---------------- layer4: fsmax + fea_of fused, channel-split, vectorized ----------------
template<int SPL>
__global__ __launch_bounds__(256) void eq_fsmax_fea(
    const u16* __restrict__ g, const float* __restrict__ fcin,
    const float4* __restrict__ vf, const float* __restrict__ dirs,
    const int* __restrict__ idx, float* __restrict__ outfea,
    int npts, int co) {
  constexpr int CHUNK = C4 / SPL;
  int part = blockIdx.x % SPL;
  int bq = blockIdx.x / SPL;
  int b = bq / npts;
  __shared__ float th[KNN*NA];
  __shared__ float dk[KNN][3];
  __shared__ int nb[KNN];
  __shared__ float row[CHUNK*NA];
  int tid = threadIdx.x;
  if (tid < KNN) {
    int m = idx[(size_t)bq*KNN + tid];
    nb[tid] = m;
    float4 vq = vf[bq];
    float4 vm = vf[(size_t)b*npts + m];
    float dx = vm.x - vq.x, dy = vm.y - vq.y, dz = vm.z - vq.z;
    float nrm = sqrtf((dx*dx + dy*dy) + dz*dz) + 1e-8f;
    dk[tid][0] = dx/nrm; dk[tid][1] = dy/nrm; dk[tid][2] = dz/nrm;
  }
  __syncthreads();
  if (tid < KNN*NA) {
    int k = tid / NA, a = tid % NA;
    float s = (dk[k][0]*dirs[a*3] + dk[k][1]*dirs[a*3+1]) + dk[k][2]*dirs[a*3+2];
    th[tid] = fmaxf(s, 0.f);
  }
  __syncthreads();
  int o0 = part * CHUNK;
  const float4* fcr = (const float4*)(fcin + ((size_t)bq*co + o0)*NA);
  const uint2* gb = (const uint2*)(g + (size_t)b*npts*co*NA + (size_t)o0*NA);
  int gquarter = co*NA/4;
  for (int t4 = tid; t4 < CHUNK*NA/4; t4 += 256) {
    int a = (4*t4) % NA;
    const float* tha = th + a;
    float m0=-3.0e38f, m1=-3.0e38f, m2=-3.0e38f, m3=-3.0e38f;
    #pragma unroll 5
    for (int k = 0; k < KNN; ++k) {
      uint2 pv = gb[(size_t)nb[k]*gquarter + t4];
      float4 tv = *(const float4*)(tha + k*NA);
      m0 = fmaxf(m0, tv.x*b2f((u16)(pv.x)));
      m1 = fmaxf(m1, tv.y*b2f((u16)(pv.x >> 16)));
      m2 = fmaxf(m2, tv.z*b2f((u16)(pv.y)));
      m3 = fmaxf(m3, tv.w*b2f((u16)(pv.y >> 16)));
    }
    float4 fc4 = fcr[t4];
    row[4*t4+0] = fc4.x + m0;
    row[4*t4+1] = fc4.y + m1;
    row[4*t4+2] = fc4.z + m2;
    row[4*t4+3] = fc4.w + m3;
  }
  __syncthreads();
  for (int o = tid; o < CHUNK; o += 256) {
    float m = row[o*NA];
    #pragma unroll
    for (int a = 1; a < NA; ++a) m = fmaxf(m, row[o*NA + a]);
    outfea[(size_t)bq*co + o0 + o] = m;
  }
}

// ---------------- normalize + relu (in place) + fea_of (folds BNG partials) ----------------
// (layer2 only: fm2 post-BN is consumed by linear3, so the in-place write is required)
__global__ __launch_bounds__(256) void eq_bnrelu_fea(
    u16* __restrict__ fm, const float* __restrict__ part,
    const float* __restrict__ gamma, const float* __restrict__ beta,
    float* __restrict__ outfea, int npts, int co) {
  int bq = blockIdx.x;
  int tid = threadIdx.x;
  __shared__ float sc[C3], sh[C3];
  __shared__ float row[C3*NA];
  for (int o = tid; o < co; o += 256) {
    float s = 0.f, s2 = 0.f;
    for (int g = 0; g < BNG; ++g) {
      s  += part[(size_t)g*2*co + o];
      s2 += part[(size_t)g*2*co + co + o];
    }
    float cnt = (float)(Bz*npts*NA);
    float mean = s / cnt;
    float var = fmaxf(s2 / cnt - mean*mean, 0.f);
    float inv = 1.0f / sqrtf(var + 1e-5f);
    sc[o] = gamma[o] * inv;
    sh[o] = beta[o] - mean * gamma[o] * inv;
  }
  __syncthreads();
  uint2* p = (uint2*)(fm + (size_t)bq*co*NA);
  int quarter = co*NA/4;
  for (int t4 = tid; t4 < quarter; t4 += 256) {
    int o = (4*t4) / NA;            // quad never straddles o-row
    float s = sc[o], h = sh[o];
    uint2 pv = p[t4];
    float v0 = fmaxf(b2f((u16)pv.x)*s + h, 0.f);
    float v1 = fmaxf(b2f((u16)(pv.x >> 16))*s + h, 0.f);
    float v2 = fmaxf(b2f((u16)pv.y)*s + h, 0.f);
    float v3 = fmaxf(b2f((u16)(pv.y >> 16))*s + h, 0.f);
    uint2 r; r.x = packb(v0, v1); r.y = packb(v2, v3);
    p[t4] = r;
    row[4*t4+0] = v0; row[4*t4+1] = v1; row[4*t4+2] = v2; row[4*t4+3] = v3;
  }
  __syncthreads();
  for (int o = tid; o < co; o += 256) {
    float m = row[o*NA];
    #pragma unroll
    for (int a = 1; a < NA; ++a) m = fmaxf(m, row[o*NA + a]);
    outfea[(size_t)bq*co + o] = m;
  }
}

// ---------------- fused BN+relu+fea+pool (layers 1 & 3: fm post-BN has no other consumer) ----
__global__ __launch_bounds__(256) void eq_bnfea_pool(
    const u16* __restrict__ fm, const float* __restrict__ part,
    const float* __restrict__ gamma, const float* __restrict__ beta,
    const int* __restrict__ idx, float* __restrict__ outfea,
    u16* __restrict__ fmp, int npts, int co) {
  int bq = blockIdx.x;
  int b = bq / npts, q = bq % npts;
  int tid = threadIdx.x;
  __shared__ float sc[C3], sh[C3];
  __shared__ float row[C3*NA];
  __shared__ int nb[4];
  for (int o = tid; o < co; o += 256) {
    float s = 0.f, s2 = 0.f;
    for (int g = 0; g < BNG; ++g) {
      s  += part[(size_t)g*2*co + o];
      s2 += part[(size_t)g*2*co + co + o];
    }
    float cnt = (float)(Bz*npts*NA);
    float mean = s / cnt;
    float var = fmaxf(s2 / cnt - mean*mean, 0.f);
    float inv = 1.0f / sqrtf(var + 1e-5f);
    sc[o] = gamma[o] * inv;
    sh[o] = beta[o] - mean * gamma[o] * inv;
  }
  bool do_pool = ((q & 3) == 0);       // POOL_RATE = 4
  if (do_pool && tid < 4) nb[tid] = idx[(size_t)bq*KNN + tid];  // POOL_K = 4 nearest
  __syncthreads();
  int quarter = co*NA/4;
  const uint2* own = (const uint2*)(fm + (size_t)bq*co*NA);
  const uint2* base = (const uint2*)(fm + (size_t)b*npts*co*NA);
  uint2* dst = (uint2*)(fmp + ((size_t)b*(npts/4) + (q >> 2))*co*NA);
  for (int t4 = tid; t4 < quarter; t4 += 256) {
    int o = (4*t4) / NA;               // quad never straddles o-row
    float s = sc[o], h = sh[o];
    uint2 pv = own[t4];
    float v0 = fmaxf(b2f((u16)pv.x)*s + h, 0.f);
    float v1 = fmaxf(b2f((u16)(pv.x >> 16))*s + h, 0.f);
    float v2 = fmaxf(b2f((u16)pv.y)*s + h, 0.f);
    float v3 = fmaxf(b2f((u16)(pv.y >> 16))*s + h, 0.f);
    row[4*t4+0] = v0; row[4*t4+1] = v1; row[4*t4+2] = v2; row[4*t4+3] = v3;
    if (do_pool) {
      float m0=v0, m1=v1, m2=v2, m3=v3;
      #pragma unroll
      for (int kk = 0; kk < 4; ++kk) {
        uint2 w = base[(size_t)nb[kk]*quarter + t4];
        m0 = fmaxf(m0, fmaxf(b2f((u16)w.x)*s + h, 0.f));
        m1 = fmaxf(m1, fmaxf(b2f((u16)(w.x >> 16))*s + h, 0.f));
        m2 = fmaxf(m2, fmaxf(b2f((u16)w.y)*s + h, 0.f));
        m3 = fmaxf(m3, fmaxf(b2f((u16)(w.y >> 16))*s + h, 0.f));
      }
      uint2 r; r.x = packb(m0, m1); r.y = packb(m2, m3);
      dst[t4] = r;
    }
  }
  __syncthreads();
  for (int o = tid; o < co; o += 256) {
    float m = row[o*NA];
    #pragma unroll
    for (int a = 1; a < NA; ++a) m = fmaxf(m, row[o*NA + a]);
    outfea[(size_t)bq*co + o] = m;
  }
}

// ---------------- host orchestration ----------------
extern "C" void kernel_launch(void* const* d_in, const int* in_sizes, int n_in,
                              void* d_out, int out_size, void* d_ws, size_t ws_size,
                              hipStream_t stream) {
  float* ws = (float*)d_ws;
  float* out = (float*)d_out;
  u16* arena = (u16*)(ws + OFF_HALF);

  InPtrs ip;
  for (int i = 0; i < 24; ++i) ip.p[i] = d_in[i];

  float4* v0f = (float4*)(ws + OFF_V0F);
  float4* v1f = (float4*)(ws + OFF_V1F);
  float4* v2f = (float4*)(ws + OFF_V2F);
  int* idx0 = (int*)(ws + OFF_IDX0);
  int* idx1 = (int*)(ws + OFF_IDX1);
  int* idx2 = (int*)(ws + OFF_IDX2);
  u16* bufA = arena + HA;            // fm0 -> fm2
  u16* bufB = arena + HB;            // fm1 -> fm3 (stays RAW pre-BN now)
  float* fc4f = (float*)(arena + HB);// layer4 fc carrier (fm3 dead by then)
  u16* bufG = arena + HG;            // g (Ws-transformed)
  u16* bufP = arena + HP;            // fmp1/fmp2 (upper half of G)
  float* partA = ws + OFF_PART;            // 32 x 2*C1
  float* partB = ws + OFF_PART + 4096;     // 32 x 2*C2
  float* partC = ws + OFF_PART + 12288;    // 32 x 2*C3
  const float* DIRS = ws + OFF_DIRS;

  // 0) convert all inputs (self dtype-detect; zeroes bn partials; v1f/v2f subsamples)
  {
    int total = Bz*N0 + 351312 + (int)PART_SZ;
    eq_convert_all<<<(total + 255)/256, 256, 0, stream>>>(ip, ws);
  }

  // 1) all 3 KNN levels in one dispatch (all depend only on convert)
  eq_knn_all<<<Bz*N0/4 + Bz*N1/4 + Bz*N2/4, 256, 0, stream>>>(v0f, idx0, v1f, idx1, v2f, idx2);
  eq_conv_surface<<<Bz*N0, 128, 0, stream>>>(v0f, idx0, ws + OFF_K0F, bufA, out + OUT0);

  // 2) layer1: fm0(bufA,C0) -> fm1(bufB,C1) at N0; fused BN+fea+pool1 -> out1 + fmp1
  eq_linear4<C0, C1, u16><<<(Bz*N0/16)*2, 256, 0, stream>>>(bufA, ws + OFF_WC + 0, ws + OFF_WS + 0,
                                                            ws + OFF_BC + 0, bufB, bufG);
  eq_fsmax<<<Bz*N0, 256, 0, stream>>>(bufG, v0f, DIRS + 0, idx0, bufB, partA, N0, C1);
  eq_bnfea_pool<<<Bz*N0, 256, 0, stream>>>(bufB, partA, ws + OFF_BN + 0, ws + OFF_BN + 64,
                                           idx0, out + OUT1, bufP, N0, C1);

  // 3) layer2: fmp1(bufP,C1) -> fm2(bufA,C2) at N1 (in-place BN kept: linear3 reads fm2)
  eq_linear4<C1, C2, u16><<<(Bz*N1/8)*2, 256, 0, stream>>>(bufP, ws + OFF_WC + 2048, ws + OFF_WS + 2048,
                                                           ws + OFF_BC + 64, bufA, bufG);
  eq_fsmax<<<Bz*N1, 256, 0, stream>>>(bufG, v1f, DIRS + 36, idx1, bufA, partB, N1, C2);
  eq_bnrelu_fea<<<Bz*N1, 256, 0, stream>>>(bufA, partB, ws + OFF_BN + 128, ws + OFF_BN + 256,
                                           out + OUT2, N1, C2);

  // 4) layer3: fm2(bufA,C2) -> fm3(bufB,C3) at N1; fused BN+fea+pool2 -> out3 + fmp2
  eq_linear4<C2, C3, u16><<<(Bz*N1/4)*2, 256, 0, stream>>>(bufA, ws + OFF_WC + 10240, ws + OFF_WS + 10240,
                                                           ws + OFF_BC + 192, bufB, bufG);
  eq_fsmax<<<Bz*N1, 256, 0, stream>>>(bufG, v1f, DIRS + 72, idx1, bufB, partC, N1, C3);
  eq_bnfea_pool<<<Bz*N1, 256, 0, stream>>>(bufB, partC, ws + OFF_BN + 384, ws + OFF_BN + 640,
                                           idx1, out + OUT3, bufP, N1, C3);

  // 5) layer4: fmp2(bufP,C3) -> fc4(f32) + g; fused fsmax+fea (4-way split) -> out4
  eq_linear4<C3, C4, float><<<(Bz*N2/2)*2, 256, 0, stream>>>(bufP, ws + OFF_WC + 43008, ws + OFF_WS + 43008,
                                                             ws + OFF_BC + 448, fc4f, bufG);
  eq_fsmax_fea<4><<<Bz*N2*4, 256, 0, stream>>>(bufG, fc4f, v2f, DIRS + 108, idx2, out + OUT4, N2, C4);
}

// Round 10
// 474.377 us; speedup vs baseline: 1.0092x; 1.0092x over previous
//
#include <hip/hip_runtime.h>
#include <hip/hip_bf16.h>
#include <math.h>

typedef unsigned short u16;
typedef unsigned long long u64;
#define DEV static __device__ __forceinline__

// ---------------- problem constants ----------------
constexpr int Bz = 2, N0 = 4096, N1 = 1024, N2 = 256, KNN = 20, NA = 12;
constexpr int C0 = 32, C1 = 64, C2 = 128, C3 = 256, C4 = 512;
constexpr int BNG = 32;  // batchnorm atomic groups

// ---------------- workspace layout ----------------
constexpr size_t OFF_V0F   = 0;                       // Bz*N0 float4 (w = |p|^2)
constexpr size_t OFF_V1F   = 32768;
constexpr size_t OFF_V2F   = 40960;
constexpr size_t OFF_K0F   = 43008;                   // 1152
constexpr size_t OFF_DIRS  = 44160;                   // 144
constexpr size_t OFF_WC    = 44304;                   // 174080
constexpr size_t OFF_WS    = 218384;                  // 174080
constexpr size_t OFF_BC    = 392464;                  // 960
constexpr size_t OFF_BN    = 393424;                  // 896
constexpr size_t OFF_FLAG  = 394832;                  // 16 (unused now)
constexpr size_t OFF_IDX0  = 394848;                  // 163840 ints
constexpr size_t OFF_IDX1  = 558688;                  // 40960
constexpr size_t OFF_IDX2  = 599648;                  // 10240
constexpr size_t OFF_PART  = 609888;                  // 28672 floats
constexpr size_t PART_SZ   = 28672;
constexpr size_t OFF_HALF  = OFF_PART + PART_SZ;      // u16 arena base (float offset)

constexpr size_t HA = 0;                              // fm0/fm2
constexpr size_t HB = 3145728;                        // fm1/fm3 ; layer4: fc4 as f32
constexpr size_t HG = 9437184;                        // g1..g4
constexpr size_t HP = HG + 3145728;                   // fmp1/fmp2 (upper half of G)
constexpr size_t WTO = 15728640;                      // W split-bf16 transposed (past G high-water)

// output element offsets (float32)
constexpr size_t OUT0 = 0;
constexpr size_t OUT1 = OUT0 + (size_t)Bz*N0*C0;
constexpr size_t OUT2 = OUT1 + (size_t)Bz*N0*C1;
constexpr size_t OUT3 = OUT2 + (size_t)Bz*N1*C2;
constexpr size_t OUT4 = OUT3 + (size_t)Bz*N1*C3;

DEV float b2f(u16 v) { return __uint_as_float(((unsigned int)v) << 16); }
DEV u16 f2b(float f) {
  unsigned int u = __float_as_uint(f);
  unsigned int lsb = (u >> 16) & 1u;
  return (u16)((u + 0x7fffu + lsb) >> 16);
}
DEV unsigned packb(float a, float b) {
  return (unsigned)f2b(a) | ((unsigned)f2b(b) << 16);
}

DEV u64 shflx64(u64 v, int m) {
  int lo = __shfl_xor((int)(unsigned)v, m, 64);
  int hi = __shfl_xor((int)(unsigned)(v >> 32), m, 64);
  return ((u64)(unsigned)hi << 32) | (unsigned)lo;
}
DEV int mbcnt64(u64 m) {
  return __builtin_amdgcn_mbcnt_hi((unsigned)(m >> 32),
         __builtin_amdgcn_mbcnt_lo((unsigned)m, 0));
}

DEV void st12(float* dst, const float* v) {
  float4 a{v[0],v[1],v[2],v[3]}, b{v[4],v[5],v[6],v[7]}, c{v[8],v[9],v[10],v[11]};
  ((float4*)dst)[0] = a; ((float4*)dst)[1] = b; ((float4*)dst)[2] = c;
}
DEV void st12(u16* dst, const float* v) {
  uint2 a{packb(v[0],v[1]), packb(v[2],v[3])};
  uint2 b{packb(v[4],v[5]), packb(v[6],v[7])};
  uint2 c{packb(v[8],v[9]), packb(v[10],v[11])};
  ((uint2*)dst)[0] = a; ((uint2*)dst)[1] = b; ((uint2*)dst)[2] = c;
}

// ---------------- convert all inputs -> f32 (self dtype-detect, zero partials) ----------------
struct InPtrs { const void* p[24]; };

__global__ void eq_convert_all(InPtrs in, float* ws) {
  __shared__ int sflag;
  {
    const u16* v = (const u16*)in.p[0];
    if (threadIdx.x < 64) {
      int bad = 0;
      #pragma unroll
      for (int j = 0; j < 4; ++j) {
        unsigned u = v[threadIdx.x*4 + j];
        int ex = (u >> 7) & 0xFF;
        bad += (((u & 0x7FFFu) != 0u) && (ex < 64 || ex > 191)) ? 1 : 0;
      }
      int tot = bad;
      #pragma unroll
      for (int s = 32; s > 0; s >>= 1) tot += __shfl_xor(tot, s, 64);
      if (threadIdx.x == 0) sflag = (tot >= 8) ? 1 : 0;   // 1 => inputs are f32
    }
    __syncthreads();
  }
  int f32mode = sflag;
  int t = blockIdx.x * blockDim.x + threadIdx.x;
  if (t < Bz*N0) {      // one thread per point; w = |p|^2
    float x, y, z;
    if (f32mode) { const float* v = (const float*)in.p[0]; x=v[t*3]; y=v[t*3+1]; z=v[t*3+2]; }
    else { const u16* v = (const u16*)in.p[0]; x=b2f(v[t*3]); y=b2f(v[t*3+1]); z=b2f(v[t*3+2]); }
    float4 o; o.x=x; o.y=y; o.z=z; o.w=(x*x + y*y) + z*z;
    ((float4*)(ws + OFF_V0F))[t] = o;
    int b = t / N0, i = t % N0;
    if ((i & 3) == 0)  ((float4*)(ws + OFF_V1F))[b*N1 + (i >> 2)] = o;
    if ((i & 15) == 0) ((float4*)(ws + OFF_V2F))[b*N2 + (i >> 4)] = o;
    return;
  }
  int r = t - Bz*N0;
  if (r >= 351312) {    // tail range zeroes bn partials
    int z = r - 351312;
    if (z < (int)PART_SZ) ws[OFF_PART + z] = 0.f;
    return;
  }
  const int cnt[23] = {1152, 36,2048,64,2048, 36,8192,128,8192,
                       36,32768,256,32768, 36,131072,512,131072,
                       64,64,128,128,256,256};
  const size_t off[23] = {OFF_K0F,
    OFF_DIRS+0,   OFF_WC+0,     OFF_BC+0,   OFF_WS+0,
    OFF_DIRS+36,  OFF_WC+2048,  OFF_BC+64,  OFF_WS+2048,
    OFF_DIRS+72,  OFF_WC+10240, OFF_BC+192, OFF_WS+10240,
    OFF_DIRS+108, OFF_WC+43008, OFF_BC+448, OFF_WS+43008,
    OFF_BN+0, OFF_BN+64, OFF_BN+128, OFF_BN+256, OFF_BN+384, OFF_BN+640};
  for (int i = 0; i < 23; ++i) {
    if (r < cnt[i]) {
      float val = f32mode ? ((const float*)in.p[i+1])[r] : b2f(((const u16*)in.p[i+1])[r]);
      ws[off[i] + r] = val;
      return;
    }
    r -= cnt[i];
  }
}

// ---------------- W prep: split-bf16 (hi+lo), transposed to [CO][CI] per layer --------------
// W = b2f(hi) + b2f(lo) to ~2^-16 relative; MFMA B-frags then read contiguous K.
__global__ void eq_wprep(const float* __restrict__ ws,
    u16* __restrict__ ch, u16* __restrict__ cl,
    u16* __restrict__ sh, u16* __restrict__ sl) {
  int e = blockIdx.x*256 + threadIdx.x;
  if (e >= 174080) return;
  const int co[4] = {64,128,256,512};
  const int ci[4] = {32,64,128,256};
  const int off[4] = {0,2048,10240,43008};
  int li = 0, loc = e;
  if (e >= 43008) { li = 3; loc = e - 43008; }
  else if (e >= 10240) { li = 2; loc = e - 10240; }
  else if (e >= 2048) { li = 1; loc = e - 2048; }
  int c = loc / co[li], o = loc % co[li];
  size_t dst = (size_t)off[li] + (size_t)o*ci[li] + c;
  float wc = ws[OFF_WC + e];
  u16 h = f2b(wc); u16 l = f2b(wc - b2f(h));
  ch[dst] = h; cl[dst] = l;
  float wv = ws[OFF_WS + e];
  h = f2b(wv); l = f2b(wv - b2f(h));
  sh[dst] = h; sl[dst] = l;
}

// ---------------- KNN v9: v8 main pass + fast exact re-enumeration fallback ----------------
// exact monotone-uint squared distance; fmaf-pinned (identical in all passes)
DEV unsigned cand_ud(const float4 vq, const float4 vc) {
  float dt = fmaf(vq.x, vc.x, fmaf(vq.y, vc.y, vq.z*vc.z));
  float d  = fmaf(-2.0f, dt, vq.w + vc.w);
  unsigned u = __float_as_uint(d);
  return u ^ ((unsigned)(((int)u) >> 31) | 0x80000000u);
}

// exact sorted-insert into network A/B (round-0 proven cndmask network)
#define INSA(u,c) do { bool lt1=(u)<dA1, lt2=(u)<dA2, lt3=(u)<dA3, lt4=(u)<dA4; \
  dA4=lt3?dA3:(lt4?(u):dA4); iA4=lt3?iA3:(lt4?(c):iA4); \
  dA3=lt2?dA2:(lt3?(u):dA3); iA3=lt2?iA2:(lt3?(c):iA3); \
  dA2=lt1?dA1:(lt2?(u):dA2); iA2=lt1?iA1:(lt2?(c):iA2); \
  dA1=lt1?(u):dA1;           iA1=lt1?(c):iA1; } while(0)
#define INSB(u,c) do { bool lt1=(u)<dB1, lt2=(u)<dB2, lt3=(u)<dB3, lt4=(u)<dB4; \
  dB4=lt3?dB3:(lt4?(u):dB4); iB4=lt3?iB3:(lt4?(c):iB4); \
  dB3=lt2?dB2:(lt3?(u):dB3); iB3=lt2?iB2:(lt3?(c):iB3); \
  dB2=lt1?dB1:(lt2?(u):dB2); iB2=lt1?iB1:(lt2?(c):iB2); \
  dB1=lt1?(u):dB1;           iB1=lt1?(c):iB1; } while(0)

// ballot-compact one candidate (ud,cc) with ud <= p into selw (128 slots)
#define CMP1(uu,cc) do { bool sel=(uu)<=p; u64 m=__ballot(sel); \
  int pos = base2 + mbcnt64(m); \
  if (sel && pos < 128) selw[pos] = ((u64)(uu) << 32) | (unsigned)(cc); \
  base2 += __popcll(m); } while(0)

template<int NPTS>
DEV void knn_body(int blk, const float4* __restrict__ vf, int* __restrict__ idx_out,
                  char* smem) {
  constexpr int CPL = NPTS/64;       // candidates per lane
  constexpr int HC  = CPL/2;         // candidates per network
  int wave = threadIdx.x >> 6, lane = threadIdx.x & 63;
  u64* selw = (u64*)smem + wave*128;
  int* extrw = (int*)(smem + 4*128*8) + wave*24;
  int qid = blk*4 + wave;
  int b = qid / NPTS, q = qid % NPTS;
  const float4* vb = vf + (size_t)b*NPTS;
  float4 vq = vb[q];

  unsigned dA1=~0u,dA2=~0u,dA3=~0u,dA4=~0u; int iA1=0,iA2=0,iA3=0,iA4=0;
  unsigned dB1=~0u,dB2=~0u,dB3=~0u,dB4=~0u; int iB1=0,iB2=0,iB3=0,iB4=0;

  if (CPL >= 8) {
    for (int jb = 0; jb < CPL; jb += 8) {
      int base = jb*64 + lane;
      float4 c0 = vb[base];
      float4 c1 = vb[base + 64];
      float4 c2 = vb[base + 128];
      float4 c3 = vb[base + 192];
      float4 c4 = vb[base + 256];
      float4 c5 = vb[base + 320];
      float4 c6 = vb[base + 384];
      float4 c7 = vb[base + 448];
      unsigned u0 = cand_ud(vq, c0);
      unsigned u1 = cand_ud(vq, c1);
      unsigned u2 = cand_ud(vq, c2);
      unsigned u3 = cand_ud(vq, c3);
      unsigned u4 = cand_ud(vq, c4);
      unsigned u5 = cand_ud(vq, c5);
      unsigned u6 = cand_ud(vq, c6);
      unsigned u7 = cand_ud(vq, c7);
      INSA(u0, base);       INSB(u1, base + 64);
      INSA(u2, base + 128); INSB(u3, base + 192);
      INSA(u4, base + 256); INSB(u5, base + 320);
      INSA(u6, base + 384); INSB(u7, base + 448);
    }
  } else {
    int base = lane;
    float4 c0 = vb[base];
    float4 c1 = vb[base + 64];
    float4 c2 = vb[base + 128];
    float4 c3 = vb[base + 192];
    unsigned u0 = cand_ud(vq, c0);
    unsigned u1 = cand_ud(vq, c1);
    unsigned u2 = cand_ud(vq, c2);
    unsigned u3 = cand_ud(vq, c3);
    INSA(u0, base);       INSB(u1, base + 64);
    INSA(u2, base + 128); INSB(u3, base + 192);
  }

  unsigned p = 0;
  for (int bit = 31; bit >= 0; --bit) {
    unsigned T = p | (1u << bit);
    int cnt = __popcll(__ballot(dA1 < T)) + __popcll(__ballot(dA2 < T))
            + __popcll(__ballot(dA3 < T)) + __popcll(__ballot(dA4 < T))
            + __popcll(__ballot(dB1 < T)) + __popcll(__ballot(dB2 < T))
            + __popcll(__ballot(dB3 < T)) + __popcll(__ballot(dB4 < T));
    if (cnt < KNN+1) p = T;
  }
  size_t obase = (size_t)qid*KNN;
  bool need_fb = (HC > 4) &&
                 ((__ballot(dA4 <= p) | __ballot(dB4 <= p)) != 0ULL);

  if (!need_fb) {
    bool pA1=dA1<=p, pA2=dA2<=p, pA3=dA3<=p, pA4=dA4<=p;
    bool pB1=dB1<=p, pB2=dB2<=p, pB3=dB3<=p, pB4=dB4<=p;
    u64 m1=__ballot(pA1), m2=__ballot(pA2), m3=__ballot(pA3), m4=__ballot(pA4);
    u64 m5=__ballot(pB1), m6=__ballot(pB2), m7=__ballot(pB3), m8=__ballot(pB4);
    int c1=__popcll(m1), c2=__popcll(m2), c3=__popcll(m3), c4=__popcll(m4);
    int c5=__popcll(m5), c6=__popcll(m6), c7=__popcll(m7), c8=__popcll(m8);
    int S = ((c1+c2)+(c3+c4)) + ((c5+c6)+(c7+c8));
    if (S > 127) need_fb = true;
    else {
      int o1=c1, o2=o1+c2, o3=o2+c3, o4=o3+c4, o5=o4+c5, o6=o5+c6, o7=o6+c7;
      if (pA1) selw[mbcnt64(m1)]      = ((u64)dA1 << 32) | (unsigned)iA1;
      if (pA2) selw[o1 + mbcnt64(m2)] = ((u64)dA2 << 32) | (unsigned)iA2;
      if (pA3) selw[o2 + mbcnt64(m3)] = ((u64)dA3 << 32) | (unsigned)iA3;
      if (pA4) selw[o3 + mbcnt64(m4)] = ((u64)dA4 << 32) | (unsigned)iA4;
      if (pB1) selw[o4 + mbcnt64(m5)] = ((u64)dB1 << 32) | (unsigned)iB1;
      if (pB2) selw[o5 + mbcnt64(m6)] = ((u64)dB2 << 32) | (unsigned)iB2;
      if (pB3) selw[o6 + mbcnt64(m7)] = ((u64)dB3 << 32) | (unsigned)iB3;
      if (pB4) selw[o7 + mbcnt64(m8)] = ((u64)dB4 << 32) | (unsigned)iB4;
      for (int sl = lane; sl < S; sl += 64) {
        u64 mykey = selw[sl];
        int rank = 0;
        for (int j2 = 0; j2 < S; ++j2) rank += (selw[j2] < mykey) ? 1 : 0;
        if (rank >= 1 && rank <= KNN)     // rank 0 = self
          idx_out[obase + rank - 1] = (int)(unsigned)(mykey & 0xFFFFFFFFu);
      }
    }
  }
  if (need_fb && CPL >= 8) {
    int base2 = 0;
    for (int jb = 0; jb < CPL; jb += 8) {
      int bidx = jb*64 + lane;
      float4 c0 = vb[bidx];
      float4 c1 = vb[bidx + 64];
      float4 c2 = vb[bidx + 128];
      float4 c3 = vb[bidx + 192];
      float4 c4 = vb[bidx + 256];
      float4 c5 = vb[bidx + 320];
      float4 c6 = vb[bidx + 384];
      float4 c7 = vb[bidx + 448];
      unsigned u0 = cand_ud(vq, c0);
      unsigned u1 = cand_ud(vq, c1);
      unsigned u2 = cand_ud(vq, c2);
      unsigned u3 = cand_ud(vq, c3);
      unsigned u4 = cand_ud(vq, c4);
      unsigned u5 = cand_ud(vq, c5);
      unsigned u6 = cand_ud(vq, c6);
      unsigned u7 = cand_ud(vq, c7);
      CMP1(u0, bidx);       CMP1(u1, bidx + 64);
      CMP1(u2, bidx + 128); CMP1(u3, bidx + 192);
      CMP1(u4, bidx + 256); CMP1(u5, bidx + 320);
      CMP1(u6, bidx + 384); CMP1(u7, bidx + 448);
    }
    if (base2 <= 127) {
      int S = base2;
      for (int sl = lane; sl < S; sl += 64) {
        u64 mykey = selw[sl];
        int rank = 0;
        for (int j2 = 0; j2 < S; ++j2) rank += (selw[j2] < mykey) ? 1 : 0;
        if (rank >= 1 && rank <= KNN)
          idx_out[obase + rank - 1] = (int)(unsigned)(mykey & 0xFFFFFFFFu);
      }
    } else {
      const u64 KINF = ~0ULL;
      u64 K1=KINF, K2=KINF, K3=KINF, K4=KINF;
      for (int j = 0; j < CPL; ++j) {
        int c = j*64 + lane;
        u64 k = ((u64)cand_ud(vq, vb[c]) << 32) | (unsigned)c;
        bool lt1 = k < K1, lt2 = k < K2, lt3 = k < K3, lt4 = k < K4;
        K4 = lt3 ? K3 : (lt4 ? k : K4);
        K3 = lt2 ? K2 : (lt3 ? k : K3);
        K2 = lt1 ? K1 : (lt2 ? k : K2);
        K1 = lt1 ? k  : K1;
      }
      for (int r = 0; r < KNN+1; ++r) {
        u64 g = K1;
        #pragma unroll
        for (int s = 32; s; s >>= 1) { u64 o = shflx64(g, s); g = (o < g) ? o : g; }
        int gidx = (int)(unsigned)(g & 0xFFFFFFFFu);
        if (lane == 0) {
          extrw[r] = gidx;
          if (r > 0) idx_out[obase + r - 1] = gidx;
        }
        if (r < KNN && lane == (gidx & 63)) {
          K1 = K2; K2 = K3; K3 = K4; K4 = KINF;
          if (K1 == KINF) {
            for (int j = 0; j < CPL; ++j) {
              int c = j*64 + lane;
              u64 k = ((u64)cand_ud(vq, vb[c]) << 32) | (unsigned)c;
              bool ex = false;
              for (int e = 0; e <= r; ++e) ex |= (extrw[e] == c);
              if (!ex) {
                bool lt1 = k < K1, lt2 = k < K2, lt3 = k < K3, lt4 = k < K4;
                K4 = lt3 ? K3 : (lt4 ? k : K4);
                K3 = lt2 ? K2 : (lt3 ? k : K3);
                K2 = lt1 ? K1 : (lt2 ? k : K2);
                K1 = lt1 ? k  : K1;
              }
            }
          }
        }
      }
    }
  }
}

// ---------------- fused KNN: all 3 levels in one dispatch ----------------
__global__ __launch_bounds__(256) void eq_knn_all(
    const float4* __restrict__ v0, int* __restrict__ i0,
    const float4* __restrict__ v1, int* __restrict__ i1,
    const float4* __restrict__ v2, int* __restrict__ i2) {
  __shared__ __align__(16) char smem[4*128*8 + 4*24*4];
  int blk = blockIdx.x;
  constexpr int NB0 = Bz*N0/4, NB1 = Bz*N1/4;
  if (blk < NB0)            knn_body<N0>(blk, v0, i0, smem);
  else if (blk < NB0+NB1)   knn_body<N1>(blk - NB0, v1, i1, smem);
  else                      knn_body<N2>(blk - NB0 - NB1, v2, i2, smem);
}

// ---------------- conv_surface + relu + fea_of(fm0), vectorized stores ----------------
__global__ __launch_bounds__(128) void eq_conv_surface(
    const float4* __restrict__ v0f, const int* __restrict__ idx0,
    const float* __restrict__ K0f, u16* __restrict__ fm0, float* __restrict__ out0) {
  int bq = blockIdx.x;          // b*N0 + q
  int b = bq >> 12;
  __shared__ float dk[KNN][3];
  __shared__ float row[C0*NA];
  int tid = threadIdx.x;
  if (tid < KNN) {
    int m = idx0[(size_t)bq*KNN + tid];
    float4 vq = v0f[bq];
    float4 vm = v0f[(size_t)b*N0 + m];
    float dx = vm.x - vq.x, dy = vm.y - vq.y, dz = vm.z - vq.z;
    float nrm = sqrtf((dx*dx + dy*dy) + dz*dz) + 1e-8f;
    dk[tid][0] = dx/nrm; dk[tid][1] = dy/nrm; dk[tid][2] = dz/nrm;
  }
  __syncthreads();
  for (int t4 = tid; t4 < C0*NA/4; t4 += 128) {
    const float* kd = K0f + (size_t)t4*12;
    float4 k0 = *(const float4*)(kd);
    float4 k1 = *(const float4*)(kd + 4);
    float4 k2 = *(const float4*)(kd + 8);
    float m0=0.f, m1=0.f, m2=0.f, m3=0.f;   // relu then max => >= 0
    #pragma unroll
    for (int k = 0; k < KNN; ++k) {
      float dx = dk[k][0], dy = dk[k][1], dz = dk[k][2];
      m0 = fmaxf(m0, (dx*k0.x + dy*k0.y) + dz*k0.z);
      m1 = fmaxf(m1, (dx*k0.w + dy*k1.x) + dz*k1.y);
      m2 = fmaxf(m2, (dx*k1.z + dy*k1.w) + dz*k2.x);
      m3 = fmaxf(m3, (dx*k2.y + dy*k2.z) + dz*k2.w);
    }
    uint2 r; r.x = packb(m0, m1); r.y = packb(m2, m3);
    ((uint2*)fm0)[(size_t)bq*(C0*NA/4) + t4] = r;
    row[4*t4+0] = m0; row[4*t4+1] = m1; row[4*t4+2] = m2; row[4*t4+3] = m3;
  }
  __syncthreads();
  if (tid < C0) {
    float m = row[tid*NA];
    #pragma unroll
    for (int a = 1; a < NA; ++a) m = fmaxf(m, row[tid*NA + a]);
    out0[(size_t)bq*C0 + tid] = m;
  }
}

// ---------------- linear v6: MFMA bf16 split-weight GEMM ----------------
// out[pt][o][a] = sum_c in[pt][c][a] * W[c][o] (+bias if mat0)
// A[m = a*PT+pt][k = c] staged in LDS; B from WT[o][c] bf16 hi+lo (prepped).
// MFMA 16x16x32 bf16, f32 acc; lane maps: A/B (row/col = lane&15, k = 8*(lane>>4)+j),
// C/D (col = lane&15, row = (lane>>4)*4 + j)  [HW-verified m89].
typedef __attribute__((ext_vector_type(8))) short bf16x8;
typedef __attribute__((ext_vector_type(4))) float f32x4;

DEV void store1(float* p, float v) { *p = v; }
DEV void store1(u16* p, float v) { *p = f2b(v); }

template<int CI, int CO, int PT, typename TO>
__global__ __launch_bounds__(256) void eq_linear_mfma(
    const u16* __restrict__ in,
    const u16* __restrict__ wc_hi, const u16* __restrict__ wc_lo,
    const u16* __restrict__ ws_hi, const u16* __restrict__ ws_lo,
    const float* __restrict__ bias, TO* __restrict__ fc, u16* __restrict__ g) {
  constexpr int MR = 12*PT;          // M rows per block
  constexpr int TM = MR/16;          // M tiles
  constexpr int TN = CO/16;          // N tiles
  constexpr int KF = CI/32;          // K frags
  constexpr int RS = CI + 8;         // LDS row stride (u16); +8 => 2-way banks (free)
  __shared__ u16 As[MR*RS];
  int tid = threadIdx.x;
  int mat = blockIdx.x & 1;
  int pt0 = (blockIdx.x >> 1) * PT;
  // stage A: in[pt0+pt][c][a] -> As[(a*PT+pt)*RS + c]; uint covers (c,a),(c,a+1), a even
  constexpr int EU = PT*CI*12/2;
  const unsigned* inw = (const unsigned*)(in + (size_t)pt0*CI*12);
  for (int t = tid; t < EU; t += 256) {
    unsigned v = inw[t];
    int e = 2*t;
    int pt = e / (CI*12), r = e % (CI*12);
    int c = r / 12, a = r % 12;
    As[(a*PT + pt)*RS + c] = (u16)v;
    As[((a+1)*PT + pt)*RS + c] = (u16)(v >> 16);
  }
  __syncthreads();
  int wave = tid >> 6, lane = tid & 63;
  int lr = lane & 15;                // A row / B col / D col
  int lk = lane >> 4;                // k-group (8 elems each)
  const u16* Whi = mat ? ws_hi : wc_hi;
  const u16* Wlo = mat ? ws_lo : wc_lo;
  for (int tp = wave; tp < TM*TN; tp += 4) {
    int mt = tp % TM, nt = tp / TM;
    int n0 = nt*16;
    f32x4 acc = {0.f, 0.f, 0.f, 0.f};
    #pragma unroll
    for (int kf = 0; kf < KF; ++kf) {
      bf16x8 af = *(const bf16x8*)&As[(mt*16 + lr)*RS + kf*32 + lk*8];
      bf16x8 bh = *(const bf16x8*)&Whi[(size_t)(n0 + lr)*CI + kf*32 + lk*8];
      bf16x8 bl = *(const bf16x8*)&Wlo[(size_t)(n0 + lr)*CI + kf*32 + lk*8];
      acc = __builtin_amdgcn_mfma_f32_16x16x32_bf16(af, bh, acc, 0, 0, 0);
      acc = __builtin_amdgcn_mfma_f32_16x16x32_bf16(af, bl, acc, 0, 0, 0);
    }
    int n = n0 + lr;
    float bv = (mat == 0) ? bias[n] : 0.f;
    #pragma unroll
    for (int j = 0; j < 4; ++j) {
      int m = mt*16 + lk*4 + j;
      int a = m / PT, pt = m % PT;
      float v = acc[j] + bv;
      size_t oaddr = ((size_t)(pt0 + pt)*CO + n)*NA + a;
      if (mat == 0) store1(fc + oaddr, v);
      else          store1(g + oaddr, v);
    }
  }
}

// ---------------- fsmax + fused BN partial stats (unroll 5, f4 th loads) ----------------
__global__ __launch_bounds__(256) void eq_fsmax(
    const u16* __restrict__ g, const float4* __restrict__ vf,
    const float* __restrict__ dirs, const int* __restrict__ idx,
    u16* __restrict__ out, float* __restrict__ part, int npts, int co) {
  int bq = blockIdx.x;
  int b = bq / npts;
  __shared__ float th[KNN*NA];
  __shared__ float dk[KNN][3];
  __shared__ int nb[KNN];
  __shared__ float sstat[2][C3];     // co <= 256
  int tid = threadIdx.x;
  if (tid < KNN) {
    int m = idx[(size_t)bq*KNN + tid];
    nb[tid] = m;
    float4 vq = vf[bq];
    float4 vm = vf[(size_t)b*npts + m];
    float dx = vm.x - vq.x, dy = vm.y - vq.y, dz = vm.z - vq.z;
    float nrm = sqrtf((dx*dx + dy*dy) + dz*dz) + 1e-8f;
    dk[tid][0] = dx/nrm; dk[tid][1] = dy/nrm; dk[tid][2] = dz/nrm;
  }
  sstat[0][tid] = 0.f; sstat[1][tid] = 0.f;
  __syncthreads();
  if (tid < KNN*NA) {
    int k = tid / NA, a = tid % NA;
    float s = (dk[k][0]*dirs[a*3] + dk[k][1]*dirs[a*3+1]) + dk[k][2]*dirs[a*3+2];
    th[tid] = fmaxf(s, 0.f);
  }
  __syncthreads();
  int quarter = co*NA/4;
  uint2* dst = (uint2*)(out + (size_t)bq*co*NA);
  const uint2* gb = (const uint2*)(g + (size_t)b*npts*co*NA);
  for (int t4 = tid; t4 < quarter; t4 += 256) {
    int a = (4*t4) % NA;          // 0, 4, or 8 — quad never straddles an o-row
    const float* tha = th + a;
    float m0=-3.0e38f, m1=-3.0e38f, m2=-3.0e38f, m3=-3.0e38f;
    #pragma unroll 5
    for (int k = 0; k < KNN; ++k) {
      uint2 pv = gb[(size_t)nb[k]*quarter + t4];
      float4 tv = *(const float4*)(tha + k*NA);   // 16B-aligned: a%4==0, 48|k*NA*4
      m0 = fmaxf(m0, tv.x*b2f((u16)(pv.x)));
      m1 = fmaxf(m1, tv.y*b2f((u16)(pv.x >> 16)));
      m2 = fmaxf(m2, tv.z*b2f((u16)(pv.y)));
      m3 = fmaxf(m3, tv.w*b2f((u16)(pv.y >> 16)));
    }
    uint2 d = dst[t4];
    float v0 = b2f((u16)d.x) + m0;
    float v1 = b2f((u16)(d.x >> 16)) + m1;
    float v2 = b2f((u16)d.y) + m2;
    float v3 = b2f((u16)(d.y >> 16)) + m3;
    uint2 r; r.x = packb(v0, v1); r.y = packb(v2, v3);
    dst[t4] = r;
    int ch = t4 / 3;              // NA/4 = 3 quads per channel
    atomicAdd(&sstat[0][ch], (v0 + v1) + (v2 + v3));
    atomicAdd(&sstat[1][ch], (v0*v0 + v1*v1) + (v2*v2 + v3*v3));
  }
  __syncthreads();
  if (tid < co) {
    float* pg = part + (size_t)(bq & (BNG-1))*2*co;
    atomicAdd(&pg[tid], sstat[0][tid]);
    atomicAdd(&pg[co + tid], sstat[1][tid]);
  }
}

// ---------------- layer4: fsmax + fea_of fused, channel-split, vectorized ----------------
template<int SPL>
__global__ __launch_bounds__(256) void eq_fsmax_fea(
    const u16* __restrict__ g, const float* __restrict__ fcin,
    const float4* __restrict__ vf, const float* __restrict__ dirs,
    const int* __restrict__ idx, float* __restrict__ outfea,
    int npts, int co) {
  constexpr int CHUNK = C4 / SPL;
  int part = blockIdx.x % SPL;
  int bq = blockIdx.x / SPL;
  int b = bq / npts;
  __shared__ float th[KNN*NA];
  __shared__ float dk[KNN][3];
  __shared__ int nb[KNN];
  __shared__ float row[CHUNK*NA];
  int tid = threadIdx.x;
  if (tid < KNN) {
    int m = idx[(size_t)bq*KNN + tid];
    nb[tid] = m;
    float4 vq = vf[bq];
    float4 vm = vf[(size_t)b*npts + m];
    float dx = vm.x - vq.x, dy = vm.y - vq.y, dz = vm.z - vq.z;
    float nrm = sqrtf((dx*dx + dy*dy) + dz*dz) + 1e-8f;
    dk[tid][0] = dx/nrm; dk[tid][1] = dy/nrm; dk[tid][2] = dz/nrm;
  }
  __syncthreads();
  if (tid < KNN*NA) {
    int k = tid / NA, a = tid % NA;
    float s = (dk[k][0]*dirs[a*3] + dk[k][1]*dirs[a*3+1]) + dk[k][2]*dirs[a*3+2];
    th[tid] = fmaxf(s, 0.f);
  }
  __syncthreads();
  int o0 = part * CHUNK;
  const float4* fcr = (const float4*)(fcin + ((size_t)bq*co + o0)*NA);
  const uint2* gb = (const uint2*)(g + (size_t)b*npts*co*NA + (size_t)o0*NA);
  int gquarter = co*NA/4;
  for (int t4 = tid; t4 < CHUNK*NA/4; t4 += 256) {
    int a = (4*t4) % NA;
    const float* tha = th + a;
    float m0=-3.0e38f, m1=-3.0e38f, m2=-3.0e38f, m3=-3.0e38f;
    #pragma unroll 5
    for (int k = 0; k < KNN; ++k) {
      uint2 pv = gb[(size_t)nb[k]*gquarter + t4];
      float4 tv = *(const float4*)(tha + k*NA);
      m0 = fmaxf(m0, tv.x*b2f((u16)(pv.x)));
      m1 = fmaxf(m1, tv.y*b2f((u16)(pv.x >> 16)));
      m2 = fmaxf(m2, tv.z*b2f((u16)(pv.y)));
      m3 = fmaxf(m3, tv.w*b2f((u16)(pv.y >> 16)));
    }
    float4 fc4 = fcr[t4];
    row[4*t4+0] = fc4.x + m0;
    row[4*t4+1] = fc4.y + m1;
    row[4*t4+2] = fc4.z + m2;
    row[4*t4+3] = fc4.w + m3;
  }
  __syncthreads();
  for (int o = tid; o < CHUNK; o += 256) {
    float m = row[o*NA];
    #pragma unroll
    for (int a = 1; a < NA; ++a) m = fmaxf(m, row[o*NA + a]);
    outfea[(size_t)bq*co + o0 + o] = m;
  }
}

// ---------------- normalize + relu (in place) + fea_of (folds BNG partials) ----------------
// (layer2 only: fm2 post-BN is consumed by linear3, so the in-place write is required)
__global__ __launch_bounds__(256) void eq_bnrelu_fea(
    u16* __restrict__ fm, const float* __restrict__ part,
    const float* __restrict__ gamma, const float* __restrict__ beta,
    float* __restrict__ outfea, int npts, int co) {
  int bq = blockIdx.x;
  int tid = threadIdx.x;
  __shared__ float sc[C3], sh[C3];
  __shared__ float row[C3*NA];
  for (int o = tid; o < co; o += 256) {
    float s = 0.f, s2 = 0.f;
    for (int g = 0; g < BNG; ++g) {
      s  += part[(size_t)g*2*co + o];
      s2 += part[(size_t)g*2*co + co + o];
    }
    float cnt = (float)(Bz*npts*NA);
    float mean = s / cnt;
    float var = fmaxf(s2 / cnt - mean*mean, 0.f);
    float inv = 1.0f / sqrtf(var + 1e-5f);
    sc[o] = gamma[o] * inv;
    sh[o] = beta[o] - mean * gamma[o] * inv;
  }
  __syncthreads();
  uint2* p = (uint2*)(fm + (size_t)bq*co*NA);
  int quarter = co*NA/4;
  for (int t4 = tid; t4 < quarter; t4 += 256) {
    int o = (4*t4) / NA;            // quad never straddles o-row
    float s = sc[o], h = sh[o];
    uint2 pv = p[t4];
    float v0 = fmaxf(b2f((u16)pv.x)*s + h, 0.f);
    float v1 = fmaxf(b2f((u16)(pv.x >> 16))*s + h, 0.f);
    float v2 = fmaxf(b2f((u16)pv.y)*s + h, 0.f);
    float v3 = fmaxf(b2f((u16)(pv.y >> 16))*s + h, 0.f);
    uint2 r; r.x = packb(v0, v1); r.y = packb(v2, v3);
    p[t4] = r;
    row[4*t4+0] = v0; row[4*t4+1] = v1; row[4*t4+2] = v2; row[4*t4+3] = v3;
  }
  __syncthreads();
  for (int o = tid; o < co; o += 256) {
    float m = row[o*NA];
    #pragma unroll
    for (int a = 1; a < NA; ++a) m = fmaxf(m, row[o*NA + a]);
    outfea[(size_t)bq*co + o] = m;
  }
}

// ---------------- fused BN+relu+fea+pool (layers 1 & 3: fm post-BN has no other consumer) ----
__global__ __launch_bounds__(256) void eq_bnfea_pool(
    const u16* __restrict__ fm, const float* __restrict__ part,
    const float* __restrict__ gamma, const float* __restrict__ beta,
    const int* __restrict__ idx, float* __restrict__ outfea,
    u16* __restrict__ fmp, int npts, int co) {
  int bq = blockIdx.x;
  int b = bq / npts, q = bq % npts;
  int tid = threadIdx.x;
  __shared__ float sc[C3], sh[C3];
  __shared__ float row[C3*NA];
  __shared__ int nb[4];
  for (int o = tid; o < co; o += 256) {
    float s = 0.f, s2 = 0.f;
    for (int g = 0; g < BNG; ++g) {
      s  += part[(size_t)g*2*co + o];
      s2 += part[(size_t)g*2*co + co + o];
    }
    float cnt = (float)(Bz*npts*NA);
    float mean = s / cnt;
    float var = fmaxf(s2 / cnt - mean*mean, 0.f);
    float inv = 1.0f / sqrtf(var + 1e-5f);
    sc[o] = gamma[o] * inv;
    sh[o] = beta[o] - mean * gamma[o] * inv;
  }
  bool do_pool = ((q & 3) == 0);       // POOL_RATE = 4
  if (do_pool && tid < 4) nb[tid] = idx[(size_t)bq*KNN + tid];  // POOL_K = 4 nearest
  __syncthreads();
  int quarter = co*NA/4;
  const uint2* own = (const uint2*)(fm + (size_t)bq*co*NA);
  const uint2* base = (const uint2*)(fm + (size_t)b*npts*co*NA);
  uint2* dst = (uint2*)(fmp + ((size_t)b*(npts/4) + (q >> 2))*co*NA);
  for (int t4 = tid; t4 < quarter; t4 += 256) {
    int o = (4*t4) / NA;               // quad never straddles o-row
    float s = sc[o], h = sh[o];
    uint2 pv = own[t4];
    float v0 = fmaxf(b2f((u16)pv.x)*s + h, 0.f);
    float v1 = fmaxf(b2f((u16)(pv.x >> 16))*s + h, 0.f);
    float v2 = fmaxf(b2f((u16)pv.y)*s + h, 0.f);
    float v3 = fmaxf(b2f((u16)(pv.y >> 16))*s + h, 0.f);
    row[4*t4+0] = v0; row[4*t4+1] = v1; row[4*t4+2] = v2; row[4*t4+3] = v3;
    if (do_pool) {
      float m0=v0, m1=v1, m2=v2, m3=v3;
      #pragma unroll
      for (int kk = 0; kk < 4; ++kk) {
        uint2 w = base[(size_t)nb[kk]*quarter + t4];
        m0 = fmaxf(m0, fmaxf(b2f((u16)w.x)*s + h, 0.f));
        m1 = fmaxf(m1, fmaxf(b2f((u16)(w.x >> 16))*s + h, 0.f));
        m2 = fmaxf(m2, fmaxf(b2f((u16)w.y)*s + h, 0.f));
        m3 = fmaxf(m3, fmaxf(b2f((u16)(w.y >> 16))*s + h, 0.f));
      }
      uint2 r; r.x = packb(m0, m1); r.y = packb(m2, m3);
      dst[t4] = r;
    }
  }
  __syncthreads();
  for (int o = tid; o < co; o += 256) {
    float m = row[o*NA];
    #pragma unroll
    for (int a = 1; a < NA; ++a) m = fmaxf(m, row[o*NA + a]);
    outfea[(size_t)bq*co + o] = m;
  }
}

// ---------------- host orchestration ----------------
extern "C" void kernel_launch(void* const* d_in, const int* in_sizes, int n_in,
                              void* d_out, int out_size, void* d_ws, size_t ws_size,
                              hipStream_t stream) {
  float* ws = (float*)d_ws;
  float* out = (float*)d_out;
  u16* arena = (u16*)(ws + OFF_HALF);

  InPtrs ip;
  for (int i = 0; i < 24; ++i) ip.p[i] = d_in[i];

  float4* v0f = (float4*)(ws + OFF_V0F);
  float4* v1f = (float4*)(ws + OFF_V1F);
  float4* v2f = (float4*)(ws + OFF_V2F);
  int* idx0 = (int*)(ws + OFF_IDX0);
  int* idx1 = (int*)(ws + OFF_IDX1);
  int* idx2 = (int*)(ws + OFF_IDX2);
  u16* bufA = arena + HA;            // fm0 -> fm2
  u16* bufB = arena + HB;            // fm1 -> fm3 (RAW pre-BN)
  float* fc4f = (float*)(arena + HB);// layer4 fc carrier (fm3 dead by then)
  u16* bufG = arena + HG;            // g (Ws-transformed)
  u16* bufP = arena + HP;            // fmp1/fmp2 (upper half of G)
  u16* wch = arena + WTO;            // Wc split-bf16 transposed hi
  u16* wcl = wch + 174080;           // Wc lo
  u16* wsh = wcl + 174080;           // Ws hi
  u16* wsl = wsh + 174080;           // Ws lo
  float* partA = ws + OFF_PART;            // 32 x 2*C1
  float* partB = ws + OFF_PART + 4096;     // 32 x 2*C2
  float* partC = ws + OFF_PART + 12288;    // 32 x 2*C3
  const float* DIRS = ws + OFF_DIRS;

  // 0) convert all inputs; then split+transpose weights for MFMA
  {
    int total = Bz*N0 + 351312 + (int)PART_SZ;
    eq_convert_all<<<(total + 255)/256, 256, 0, stream>>>(ip, ws);
  }
  eq_wprep<<<(174080 + 255)/256, 256, 0, stream>>>(ws, wch, wcl, wsh, wsl);

  // 1) all 3 KNN levels in one dispatch
  eq_knn_all<<<Bz*N0/4 + Bz*N1/4 + Bz*N2/4, 256, 0, stream>>>(v0f, idx0, v1f, idx1, v2f, idx2);
  eq_conv_surface<<<Bz*N0, 128, 0, stream>>>(v0f, idx0, ws + OFF_K0F, bufA, out + OUT0);

  // 2) layer1: fm0(bufA,C0) -> fm1(bufB,C1) at N0; fused BN+fea+pool1 -> out1 + fmp1
  eq_linear_mfma<C0, C1, 8, u16><<<(Bz*N0/8)*2, 256, 0, stream>>>(
      bufA, wch + 0, wcl + 0, wsh + 0, wsl + 0, ws + OFF_BC + 0, bufB, bufG);
  eq_fsmax<<<Bz*N0, 256, 0, stream>>>(bufG, v0f, DIRS + 0, idx0, bufB, partA, N0, C1);
  eq_bnfea_pool<<<Bz*N0, 256, 0, stream>>>(bufB, partA, ws + OFF_BN + 0, ws + OFF_BN + 64,
                                           idx0, out + OUT1, bufP, N0, C1);

  // 3) layer2: fmp1(bufP,C1) -> fm2(bufA,C2) at N1 (in-place BN kept: linear3 reads fm2)
  eq_linear_mfma<C1, C2, 8, u16><<<(Bz*N1/8)*2, 256, 0, stream>>>(
      bufP, wch + 2048, wcl + 2048, wsh + 2048, wsl + 2048, ws + OFF_BC + 64, bufA, bufG);
  eq_fsmax<<<Bz*N1, 256, 0, stream>>>(bufG, v1f, DIRS + 36, idx1, bufA, partB, N1, C2);
  eq_bnrelu_fea<<<Bz*N1, 256, 0, stream>>>(bufA, partB, ws + OFF_BN + 128, ws + OFF_BN + 256,
                                           out + OUT2, N1, C2);

  // 4) layer3: fm2(bufA,C2) -> fm3(bufB,C3) at N1; fused BN+fea+pool2 -> out3 + fmp2
  eq_linear_mfma<C2, C3, 8, u16><<<(Bz*N1/8)*2, 256, 0, stream>>>(
      bufA, wch + 10240, wcl + 10240, wsh + 10240, wsl + 10240, ws + OFF_BC + 192, bufB, bufG);
  eq_fsmax<<<Bz*N1, 256, 0, stream>>>(bufG, v1f, DIRS + 72, idx1, bufB, partC, N1, C3);
  eq_bnfea_pool<<<Bz*N1, 256, 0, stream>>>(bufB, partC, ws + OFF_BN + 384, ws + OFF_BN + 640,
                                           idx1, out + OUT3, bufP, N1, C3);

  // 5) layer4: fmp2(bufP,C3) -> fc4(f32) + g; fused fsmax+fea (4-way split) -> out4
  eq_linear_mfma<C3, C4, 4, float><<<(Bz*N2/4)*2, 256, 0, stream>>>(
      bufP, wch + 43008, wcl + 43008, wsh + 43008, wsl + 43008, ws + OFF_BC + 448, fc4f, bufG);
  eq_fsmax_fea<4><<<Bz*N2*4, 256, 0, stream>>>(bufG, fc4f, v2f, DIRS + 108, idx2, out + OUT4, N2, C4);
}

// Round 11
// 412.557 us; speedup vs baseline: 1.1604x; 1.1498x over previous
//
#include <hip/hip_runtime.h>
#include <hip/hip_bf16.h>
#include <math.h>

typedef unsigned short u16;
typedef unsigned long long u64;
#define DEV static __device__ __forceinline__

// ---------------- problem constants ----------------
constexpr int Bz = 2, N0 = 4096, N1 = 1024, N2 = 256, KNN = 20, NA = 12;
constexpr int C0 = 32, C1 = 64, C2 = 128, C3 = 256, C4 = 512;
constexpr int BNG = 32;  // batchnorm atomic groups

// ---------------- workspace layout ----------------
constexpr size_t OFF_V0F   = 0;                       // Bz*N0 float4 (w = |p|^2)
constexpr size_t OFF_V1F   = 32768;
constexpr size_t OFF_V2F   = 40960;
constexpr size_t OFF_K0F   = 43008;                   // 1152
constexpr size_t OFF_DIRS  = 44160;                   // 144
constexpr size_t OFF_WC    = 44304;                   // 174080
constexpr size_t OFF_WS    = 218384;                  // 174080
constexpr size_t OFF_BC    = 392464;                  // 960
constexpr size_t OFF_BN    = 393424;                  // 896
constexpr size_t OFF_FLAG  = 394832;                  // 16 (unused now)
constexpr size_t OFF_IDX0  = 394848;                  // 163840 ints
constexpr size_t OFF_IDX1  = 558688;                  // 40960
constexpr size_t OFF_IDX2  = 599648;                  // 10240
constexpr size_t OFF_PART  = 609888;                  // 28672 floats
constexpr size_t PART_SZ   = 28672;
constexpr size_t OFF_HALF  = OFF_PART + PART_SZ;      // u16 arena base (float offset)

constexpr size_t HA = 0;                              // fm0/fm2
constexpr size_t HB = 3145728;                        // fm1/fm3 ; layer4: fc4 as f32
constexpr size_t HG = 9437184;                        // g1..g4
constexpr size_t HP = HG + 3145728;                   // fmp1/fmp2 (upper half of G)
constexpr size_t WTO = 15728640;                      // W split-bf16 transposed (past G high-water)

// output element offsets (float32)
constexpr size_t OUT0 = 0;
constexpr size_t OUT1 = OUT0 + (size_t)Bz*N0*C0;
constexpr size_t OUT2 = OUT1 + (size_t)Bz*N0*C1;
constexpr size_t OUT3 = OUT2 + (size_t)Bz*N1*C2;
constexpr size_t OUT4 = OUT3 + (size_t)Bz*N1*C3;

DEV float b2f(u16 v) { return __uint_as_float(((unsigned int)v) << 16); }
DEV u16 f2b(float f) {
  unsigned int u = __float_as_uint(f);
  unsigned int lsb = (u >> 16) & 1u;
  return (u16)((u + 0x7fffu + lsb) >> 16);
}
DEV unsigned packb(float a, float b) {
  return (unsigned)f2b(a) | ((unsigned)f2b(b) << 16);
}

DEV u64 shflx64(u64 v, int m) {
  int lo = __shfl_xor((int)(unsigned)v, m, 64);
  int hi = __shfl_xor((int)(unsigned)(v >> 32), m, 64);
  return ((u64)(unsigned)hi << 32) | (unsigned)lo;
}
DEV int mbcnt64(u64 m) {
  return __builtin_amdgcn_mbcnt_hi((unsigned)(m >> 32),
         __builtin_amdgcn_mbcnt_lo((unsigned)m, 0));
}

DEV void st12(float* dst, const float* v) {
  float4 a{v[0],v[1],v[2],v[3]}, b{v[4],v[5],v[6],v[7]}, c{v[8],v[9],v[10],v[11]};
  ((float4*)dst)[0] = a; ((float4*)dst)[1] = b; ((float4*)dst)[2] = c;
}
DEV void st12(u16* dst, const float* v) {
  uint2 a{packb(v[0],v[1]), packb(v[2],v[3])};
  uint2 b{packb(v[4],v[5]), packb(v[6],v[7])};
  uint2 c{packb(v[8],v[9]), packb(v[10],v[11])};
  ((uint2*)dst)[0] = a; ((uint2*)dst)[1] = b; ((uint2*)dst)[2] = c;
}

// ---------------- convert all inputs -> f32 (self dtype-detect, zero partials) ----------------
struct InPtrs { const void* p[24]; };

__global__ void eq_convert_all(InPtrs in, float* ws) {
  __shared__ int sflag;
  {
    const u16* v = (const u16*)in.p[0];
    if (threadIdx.x < 64) {
      int bad = 0;
      #pragma unroll
      for (int j = 0; j < 4; ++j) {
        unsigned u = v[threadIdx.x*4 + j];
        int ex = (u >> 7) & 0xFF;
        bad += (((u & 0x7FFFu) != 0u) && (ex < 64 || ex > 191)) ? 1 : 0;
      }
      int tot = bad;
      #pragma unroll
      for (int s = 32; s > 0; s >>= 1) tot += __shfl_xor(tot, s, 64);
      if (threadIdx.x == 0) sflag = (tot >= 8) ? 1 : 0;   // 1 => inputs are f32
    }
    __syncthreads();
  }
  int f32mode = sflag;
  int t = blockIdx.x * blockDim.x + threadIdx.x;
  if (t < Bz*N0) {      // one thread per point; w = |p|^2
    float x, y, z;
    if (f32mode) { const float* v = (const float*)in.p[0]; x=v[t*3]; y=v[t*3+1]; z=v[t*3+2]; }
    else { const u16* v = (const u16*)in.p[0]; x=b2f(v[t*3]); y=b2f(v[t*3+1]); z=b2f(v[t*3+2]); }
    float4 o; o.x=x; o.y=y; o.z=z; o.w=(x*x + y*y) + z*z;
    ((float4*)(ws + OFF_V0F))[t] = o;
    int b = t / N0, i = t % N0;
    if ((i & 3) == 0)  ((float4*)(ws + OFF_V1F))[b*N1 + (i >> 2)] = o;
    if ((i & 15) == 0) ((float4*)(ws + OFF_V2F))[b*N2 + (i >> 4)] = o;
    return;
  }
  int r = t - Bz*N0;
  if (r >= 351312) {    // tail range zeroes bn partials
    int z = r - 351312;
    if (z < (int)PART_SZ) ws[OFF_PART + z] = 0.f;
    return;
  }
  const int cnt[23] = {1152, 36,2048,64,2048, 36,8192,128,8192,
                       36,32768,256,32768, 36,131072,512,131072,
                       64,64,128,128,256,256};
  const size_t off[23] = {OFF_K0F,
    OFF_DIRS+0,   OFF_WC+0,     OFF_BC+0,   OFF_WS+0,
    OFF_DIRS+36,  OFF_WC+2048,  OFF_BC+64,  OFF_WS+2048,
    OFF_DIRS+72,  OFF_WC+10240, OFF_BC+192, OFF_WS+10240,
    OFF_DIRS+108, OFF_WC+43008, OFF_BC+448, OFF_WS+43008,
    OFF_BN+0, OFF_BN+64, OFF_BN+128, OFF_BN+256, OFF_BN+384, OFF_BN+640};
  for (int i = 0; i < 23; ++i) {
    if (r < cnt[i]) {
      float val = f32mode ? ((const float*)in.p[i+1])[r] : b2f(((const u16*)in.p[i+1])[r]);
      ws[off[i] + r] = val;
      return;
    }
    r -= cnt[i];
  }
}

// ---------------- W prep: split-bf16 (hi+lo), transposed to [CO][CI] per layer --------------
__global__ void eq_wprep(const float* __restrict__ ws,
    u16* __restrict__ ch, u16* __restrict__ cl,
    u16* __restrict__ sh, u16* __restrict__ sl) {
  int e = blockIdx.x*256 + threadIdx.x;
  if (e >= 174080) return;
  const int co[4] = {64,128,256,512};
  const int ci[4] = {32,64,128,256};
  const int off[4] = {0,2048,10240,43008};
  int li = 0, loc = e;
  if (e >= 43008) { li = 3; loc = e - 43008; }
  else if (e >= 10240) { li = 2; loc = e - 10240; }
  else if (e >= 2048) { li = 1; loc = e - 2048; }
  int c = loc / co[li], o = loc % co[li];
  size_t dst = (size_t)off[li] + (size_t)o*ci[li] + c;
  float wc = ws[OFF_WC + e];
  u16 h = f2b(wc); u16 l = f2b(wc - b2f(h));
  ch[dst] = h; cl[dst] = l;
  float wv = ws[OFF_WS + e];
  h = f2b(wv); l = f2b(wv - b2f(h));
  sh[dst] = h; sl[dst] = l;
}

// ---------------- KNN v9 (kept): v8 main pass + fast exact re-enumeration fallback ----------
DEV unsigned cand_ud(const float4 vq, const float4 vc) {
  float dt = fmaf(vq.x, vc.x, fmaf(vq.y, vc.y, vq.z*vc.z));
  float d  = fmaf(-2.0f, dt, vq.w + vc.w);
  unsigned u = __float_as_uint(d);
  return u ^ ((unsigned)(((int)u) >> 31) | 0x80000000u);
}

#define INSA(u,c) do { bool lt1=(u)<dA1, lt2=(u)<dA2, lt3=(u)<dA3, lt4=(u)<dA4; \
  dA4=lt3?dA3:(lt4?(u):dA4); iA4=lt3?iA3:(lt4?(c):iA4); \
  dA3=lt2?dA2:(lt3?(u):dA3); iA3=lt2?iA2:(lt3?(c):iA3); \
  dA2=lt1?dA1:(lt2?(u):dA2); iA2=lt1?iA1:(lt2?(c):iA2); \
  dA1=lt1?(u):dA1;           iA1=lt1?(c):iA1; } while(0)
#define INSB(u,c) do { bool lt1=(u)<dB1, lt2=(u)<dB2, lt3=(u)<dB3, lt4=(u)<dB4; \
  dB4=lt3?dB3:(lt4?(u):dB4); iB4=lt3?iB3:(lt4?(c):iB4); \
  dB3=lt2?dB2:(lt3?(u):dB3); iB3=lt2?iB2:(lt3?(c):iB3); \
  dB2=lt1?dB1:(lt2?(u):dB2); iB2=lt1?iB1:(lt2?(c):iB2); \
  dB1=lt1?(u):dB1;           iB1=lt1?(c):iB1; } while(0)

#define CMP1(uu,cc) do { bool sel=(uu)<=p; u64 m=__ballot(sel); \
  int pos = base2 + mbcnt64(m); \
  if (sel && pos < 128) selw[pos] = ((u64)(uu) << 32) | (unsigned)(cc); \
  base2 += __popcll(m); } while(0)

template<int NPTS>
DEV void knn_body(int blk, const float4* __restrict__ vf, int* __restrict__ idx_out,
                  char* smem) {
  constexpr int CPL = NPTS/64;       // candidates per lane
  constexpr int HC  = CPL/2;         // candidates per network
  int wave = threadIdx.x >> 6, lane = threadIdx.x & 63;
  u64* selw = (u64*)smem + wave*128;
  int* extrw = (int*)(smem + 4*128*8) + wave*24;
  int qid = blk*4 + wave;
  int b = qid / NPTS, q = qid % NPTS;
  const float4* vb = vf + (size_t)b*NPTS;
  float4 vq = vb[q];

  unsigned dA1=~0u,dA2=~0u,dA3=~0u,dA4=~0u; int iA1=0,iA2=0,iA3=0,iA4=0;
  unsigned dB1=~0u,dB2=~0u,dB3=~0u,dB4=~0u; int iB1=0,iB2=0,iB3=0,iB4=0;

  if (CPL >= 8) {
    for (int jb = 0; jb < CPL; jb += 8) {
      int base = jb*64 + lane;
      float4 c0 = vb[base];
      float4 c1 = vb[base + 64];
      float4 c2 = vb[base + 128];
      float4 c3 = vb[base + 192];
      float4 c4 = vb[base + 256];
      float4 c5 = vb[base + 320];
      float4 c6 = vb[base + 384];
      float4 c7 = vb[base + 448];
      unsigned u0 = cand_ud(vq, c0);
      unsigned u1 = cand_ud(vq, c1);
      unsigned u2 = cand_ud(vq, c2);
      unsigned u3 = cand_ud(vq, c3);
      unsigned u4 = cand_ud(vq, c4);
      unsigned u5 = cand_ud(vq, c5);
      unsigned u6 = cand_ud(vq, c6);
      unsigned u7 = cand_ud(vq, c7);
      INSA(u0, base);       INSB(u1, base + 64);
      INSA(u2, base + 128); INSB(u3, base + 192);
      INSA(u4, base + 256); INSB(u5, base + 320);
      INSA(u6, base + 384); INSB(u7, base + 448);
    }
  } else {
    int base = lane;
    float4 c0 = vb[base];
    float4 c1 = vb[base + 64];
    float4 c2 = vb[base + 128];
    float4 c3 = vb[base + 192];
    unsigned u0 = cand_ud(vq, c0);
    unsigned u1 = cand_ud(vq, c1);
    unsigned u2 = cand_ud(vq, c2);
    unsigned u3 = cand_ud(vq, c3);
    INSA(u0, base);       INSB(u1, base + 64);
    INSA(u2, base + 128); INSB(u3, base + 192);
  }

  unsigned p = 0;
  for (int bit = 31; bit >= 0; --bit) {
    unsigned T = p | (1u << bit);
    int cnt = __popcll(__ballot(dA1 < T)) + __popcll(__ballot(dA2 < T))
            + __popcll(__ballot(dA3 < T)) + __popcll(__ballot(dA4 < T))
            + __popcll(__ballot(dB1 < T)) + __popcll(__ballot(dB2 < T))
            + __popcll(__ballot(dB3 < T)) + __popcll(__ballot(dB4 < T));
    if (cnt < KNN+1) p = T;
  }
  size_t obase = (size_t)qid*KNN;
  bool need_fb = (HC > 4) &&
                 ((__ballot(dA4 <= p) | __ballot(dB4 <= p)) != 0ULL);

  if (!need_fb) {
    bool pA1=dA1<=p, pA2=dA2<=p, pA3=dA3<=p, pA4=dA4<=p;
    bool pB1=dB1<=p, pB2=dB2<=p, pB3=dB3<=p, pB4=dB4<=p;
    u64 m1=__ballot(pA1), m2=__ballot(pA2), m3=__ballot(pA3), m4=__ballot(pA4);
    u64 m5=__ballot(pB1), m6=__ballot(pB2), m7=__ballot(pB3), m8=__ballot(pB4);
    int c1=__popcll(m1), c2=__popcll(m2), c3=__popcll(m3), c4=__popcll(m4);
    int c5=__popcll(m5), c6=__popcll(m6), c7=__popcll(m7), c8=__popcll(m8);
    int S = ((c1+c2)+(c3+c4)) + ((c5+c6)+(c7+c8));
    if (S > 127) need_fb = true;
    else {
      int o1=c1, o2=o1+c2, o3=o2+c3, o4=o3+c4, o5=o4+c5, o6=o5+c6, o7=o6+c7;
      if (pA1) selw[mbcnt64(m1)]      = ((u64)dA1 << 32) | (unsigned)iA1;
      if (pA2) selw[o1 + mbcnt64(m2)] = ((u64)dA2 << 32) | (unsigned)iA2;
      if (pA3) selw[o2 + mbcnt64(m3)] = ((u64)dA3 << 32) | (unsigned)iA3;
      if (pA4) selw[o3 + mbcnt64(m4)] = ((u64)dA4 << 32) | (unsigned)iA4;
      if (pB1) selw[o4 + mbcnt64(m5)] = ((u64)dB1 << 32) | (unsigned)iB1;
      if (pB2) selw[o5 + mbcnt64(m6)] = ((u64)dB2 << 32) | (unsigned)iB2;
      if (pB3) selw[o6 + mbcnt64(m7)] = ((u64)dB3 << 32) | (unsigned)iB3;
      if (pB4) selw[o7 + mbcnt64(m8)] = ((u64)dB4 << 32) | (unsigned)iB4;
      for (int sl = lane; sl < S; sl += 64) {
        u64 mykey = selw[sl];
        int rank = 0;
        for (int j2 = 0; j2 < S; ++j2) rank += (selw[j2] < mykey) ? 1 : 0;
        if (rank >= 1 && rank <= KNN)     // rank 0 = self
          idx_out[obase + rank - 1] = (int)(unsigned)(mykey & 0xFFFFFFFFu);
      }
    }
  }
  if (need_fb && CPL >= 8) {
    int base2 = 0;
    for (int jb = 0; jb < CPL; jb += 8) {
      int bidx = jb*64 + lane;
      float4 c0 = vb[bidx];
      float4 c1 = vb[bidx + 64];
      float4 c2 = vb[bidx + 128];
      float4 c3 = vb[bidx + 192];
      float4 c4 = vb[bidx + 256];
      float4 c5 = vb[bidx + 320];
      float4 c6 = vb[bidx + 384];
      float4 c7 = vb[bidx + 448];
      unsigned u0 = cand_ud(vq, c0);
      unsigned u1 = cand_ud(vq, c1);
      unsigned u2 = cand_ud(vq, c2);
      unsigned u3 = cand_ud(vq, c3);
      unsigned u4 = cand_ud(vq, c4);
      unsigned u5 = cand_ud(vq, c5);
      unsigned u6 = cand_ud(vq, c6);
      unsigned u7 = cand_ud(vq, c7);
      CMP1(u0, bidx);       CMP1(u1, bidx + 64);
      CMP1(u2, bidx + 128); CMP1(u3, bidx + 192);
      CMP1(u4, bidx + 256); CMP1(u5, bidx + 320);
      CMP1(u6, bidx + 384); CMP1(u7, bidx + 448);
    }
    if (base2 <= 127) {
      int S = base2;
      for (int sl = lane; sl < S; sl += 64) {
        u64 mykey = selw[sl];
        int rank = 0;
        for (int j2 = 0; j2 < S; ++j2) rank += (selw[j2] < mykey) ? 1 : 0;
        if (rank >= 1 && rank <= KNN)
          idx_out[obase + rank - 1] = (int)(unsigned)(mykey & 0xFFFFFFFFu);
      }
    } else {
      const u64 KINF = ~0ULL;
      u64 K1=KINF, K2=KINF, K3=KINF, K4=KINF;
      for (int j = 0; j < CPL; ++j) {
        int c = j*64 + lane;
        u64 k = ((u64)cand_ud(vq, vb[c]) << 32) | (unsigned)c;
        bool lt1 = k < K1, lt2 = k < K2, lt3 = k < K3, lt4 = k < K4;
        K4 = lt3 ? K3 : (lt4 ? k : K4);
        K3 = lt2 ? K2 : (lt3 ? k : K3);
        K2 = lt1 ? K1 : (lt2 ? k : K2);
        K1 = lt1 ? k  : K1;
      }
      for (int r = 0; r < KNN+1; ++r) {
        u64 g = K1;
        #pragma unroll
        for (int s = 32; s; s >>= 1) { u64 o = shflx64(g, s); g = (o < g) ? o : g; }
        int gidx = (int)(unsigned)(g & 0xFFFFFFFFu);
        if (lane == 0) {
          extrw[r] = gidx;
          if (r > 0) idx_out[obase + r - 1] = gidx;
        }
        if (r < KNN && lane == (gidx & 63)) {
          K1 = K2; K2 = K3; K3 = K4; K4 = KINF;
          if (K1 == KINF) {
            for (int j = 0; j < CPL; ++j) {
              int c = j*64 + lane;
              u64 k = ((u64)cand_ud(vq, vb[c]) << 32) | (unsigned)c;
              bool ex = false;
              for (int e = 0; e <= r; ++e) ex |= (extrw[e] == c);
              if (!ex) {
                bool lt1 = k < K1, lt2 = k < K2, lt3 = k < K3, lt4 = k < K4;
                K4 = lt3 ? K3 : (lt4 ? k : K4);
                K3 = lt2 ? K2 : (lt3 ? k : K3);
                K2 = lt1 ? K1 : (lt2 ? k : K2);
                K1 = lt1 ? k  : K1;
              }
            }
          }
        }
      }
    }
  }
}

// ---------------- fused KNN: all 3 levels in one dispatch ----------------
__global__ __launch_bounds__(256) void eq_knn_all(
    const float4* __restrict__ v0, int* __restrict__ i0,
    const float4* __restrict__ v1, int* __restrict__ i1,
    const float4* __restrict__ v2, int* __restrict__ i2) {
  __shared__ __align__(16) char smem[4*128*8 + 4*24*4];
  int blk = blockIdx.x;
  constexpr int NB0 = Bz*N0/4, NB1 = Bz*N1/4;
  if (blk < NB0)            knn_body<N0>(blk, v0, i0, smem);
  else if (blk < NB0+NB1)   knn_body<N1>(blk - NB0, v1, i1, smem);
  else                      knn_body<N2>(blk - NB0 - NB1, v2, i2, smem);
}

// ---------------- conv_surface + relu + fea_of(fm0), vectorized stores ----------------
__global__ __launch_bounds__(128) void eq_conv_surface(
    const float4* __restrict__ v0f, const int* __restrict__ idx0,
    const float* __restrict__ K0f, u16* __restrict__ fm0, float* __restrict__ out0) {
  int bq = blockIdx.x;          // b*N0 + q
  int b = bq >> 12;
  __shared__ float dk[KNN][3];
  __shared__ float row[C0*NA];
  int tid = threadIdx.x;
  if (tid < KNN) {
    int m = idx0[(size_t)bq*KNN + tid];
    float4 vq = v0f[bq];
    float4 vm = v0f[(size_t)b*N0 + m];
    float dx = vm.x - vq.x, dy = vm.y - vq.y, dz = vm.z - vq.z;
    float nrm = sqrtf((dx*dx + dy*dy) + dz*dz) + 1e-8f;
    dk[tid][0] = dx/nrm; dk[tid][1] = dy/nrm; dk[tid][2] = dz/nrm;
  }
  __syncthreads();
  for (int t4 = tid; t4 < C0*NA/4; t4 += 128) {
    const float* kd = K0f + (size_t)t4*12;
    float4 k0 = *(const float4*)(kd);
    float4 k1 = *(const float4*)(kd + 4);
    float4 k2 = *(const float4*)(kd + 8);
    float m0=0.f, m1=0.f, m2=0.f, m3=0.f;   // relu then max => >= 0
    #pragma unroll
    for (int k = 0; k < KNN; ++k) {
      float dx = dk[k][0], dy = dk[k][1], dz = dk[k][2];
      m0 = fmaxf(m0, (dx*k0.x + dy*k0.y) + dz*k0.z);
      m1 = fmaxf(m1, (dx*k0.w + dy*k1.x) + dz*k1.y);
      m2 = fmaxf(m2, (dx*k1.z + dy*k1.w) + dz*k2.x);
      m3 = fmaxf(m3, (dx*k2.y + dy*k2.z) + dz*k2.w);
    }
    uint2 r; r.x = packb(m0, m1); r.y = packb(m2, m3);
    ((uint2*)fm0)[(size_t)bq*(C0*NA/4) + t4] = r;
    row[4*t4+0] = m0; row[4*t4+1] = m1; row[4*t4+2] = m2; row[4*t4+3] = m3;
  }
  __syncthreads();
  if (tid < C0) {
    float m = row[tid*NA];
    #pragma unroll
    for (int a = 1; a < NA; ++a) m = fmaxf(m, row[tid*NA + a]);
    out0[(size_t)bq*C0 + tid] = m;
  }
}

// ---------------- linear v7: MFMA bf16, B-frags cached in regs, N split across blocks ----
// out[pt][o][a] = sum_c in[pt][c][a] * W[c][o] (+bias if mat0)
// A[m = a*PT+pt][k = c] staged in LDS; B from WT[o][c] bf16 hi+lo (prepped).
// Lane maps (HW-verified m89): A/B (row/col = lane&15, k = 8*(lane>>4)+j),
// C/D (col = lane&15, row = (lane>>4)*4 + j). MFMA order kf:{hi,lo} preserved.
typedef __attribute__((ext_vector_type(8))) short bf16x8;
typedef __attribute__((ext_vector_type(4))) float f32x4;

DEV void store1(float* p, float v) { *p = v; }
DEV void store1(u16* p, float v) { *p = f2b(v); }

template<int CI, int CO, int PT, int SPLITN, typename TO>
__global__ __launch_bounds__(256) void eq_linear_mfma(
    const u16* __restrict__ in,
    const u16* __restrict__ wc_hi, const u16* __restrict__ wc_lo,
    const u16* __restrict__ ws_hi, const u16* __restrict__ ws_lo,
    const float* __restrict__ bias, TO* __restrict__ fc, u16* __restrict__ g) {
  constexpr int MR = 12*PT;          // M rows per block
  constexpr int TM = MR/16;          // M tiles
  constexpr int TN = CO/16;          // N tiles (total)
  constexpr int NTC = TN/SPLITN;     // N tiles this block (== 4 => 1 per wave)
  constexpr int KF = CI/32;          // K frags
  constexpr int RS = CI + 8;         // LDS row stride (u16); 2-way banks (free)
  __shared__ u16 As[MR*RS];
  int tid = threadIdx.x;
  int mat = blockIdx.x & 1;
  int rest = blockIdx.x >> 1;
  int sp = rest % SPLITN;
  int pt0 = (rest / SPLITN) * PT;
  // stage A: in[pt0+pt][c][a] -> As[(a*PT+pt)*RS + c]
  constexpr int EU = PT*CI*12/2;
  const unsigned* inw = (const unsigned*)(in + (size_t)pt0*CI*12);
  for (int t = tid; t < EU; t += 256) {
    unsigned v = inw[t];
    int e = 2*t;
    int pt = e / (CI*12), r = e % (CI*12);
    int c = r / 12, a = r % 12;
    As[(a*PT + pt)*RS + c] = (u16)v;
    As[((a+1)*PT + pt)*RS + c] = (u16)(v >> 16);
  }
  __syncthreads();
  int wave = tid >> 6, lane = tid & 63;
  int lr = lane & 15;                // A row / B col / D col
  int lk = lane >> 4;                // k-group (8 elems each)
  const u16* Whi = mat ? ws_hi : wc_hi;
  const u16* Wlo = mat ? ws_lo : wc_lo;
  for (int ntl = wave; ntl < NTC; ntl += 4) {
    int nt = sp*NTC + ntl;
    int n = nt*16 + lr;
    // load B-frags ONCE per column tile (registers; static indices only)
    bf16x8 bh[KF], bl[KF];
    #pragma unroll
    for (int kf = 0; kf < KF; ++kf) {
      bh[kf] = *(const bf16x8*)&Whi[(size_t)n*CI + kf*32 + lk*8];
      bl[kf] = *(const bf16x8*)&Wlo[(size_t)n*CI + kf*32 + lk*8];
    }
    float bv = (mat == 0) ? bias[n] : 0.f;
    #pragma unroll
    for (int mt = 0; mt < TM; ++mt) {
      f32x4 acc = {0.f, 0.f, 0.f, 0.f};
      #pragma unroll
      for (int kf = 0; kf < KF; ++kf) {
        bf16x8 af = *(const bf16x8*)&As[(mt*16 + lr)*RS + kf*32 + lk*8];
        acc = __builtin_amdgcn_mfma_f32_16x16x32_bf16(af, bh[kf], acc, 0, 0, 0);
        acc = __builtin_amdgcn_mfma_f32_16x16x32_bf16(af, bl[kf], acc, 0, 0, 0);
      }
      #pragma unroll
      for (int j = 0; j < 4; ++j) {
        int m = mt*16 + lk*4 + j;
        int a = m / PT, pt = m % PT;
        float v = acc[j] + bv;
        size_t oaddr = ((size_t)(pt0 + pt)*CO + n)*NA + a;
        if (mat == 0) store1(fc + oaddr, v);
        else          store1(g + oaddr, v);
      }
    }
  }
}

// ---------------- fsmax + fused BN partial stats (unroll 5, f4 th loads) ----------------
__global__ __launch_bounds__(256) void eq_fsmax(
    const u16* __restrict__ g, const float4* __restrict__ vf,
    const float* __restrict__ dirs, const int* __restrict__ idx,
    u16* __restrict__ out, float* __restrict__ part, int npts, int co) {
  int bq = blockIdx.x;
  int b = bq / npts;
  __shared__ float th[KNN*NA];
  __shared__ float dk[KNN][3];
  __shared__ int nb[KNN];
  __shared__ float sstat[2][C3];     // co <= 256
  int tid = threadIdx.x;
  if (tid < KNN) {
    int m = idx[(size_t)bq*KNN + tid];
    nb[tid] = m;
    float4 vq = vf[bq];
    float4 vm = vf[(size_t)b*npts + m];
    float dx = vm.x - vq.x, dy = vm.y - vq.y, dz = vm.z - vq.z;
    float nrm = sqrtf((dx*dx + dy*dy) + dz*dz) + 1e-8f;
    dk[tid][0] = dx/nrm; dk[tid][1] = dy/nrm; dk[tid][2] = dz/nrm;
  }
  sstat[0][tid] = 0.f; sstat[1][tid] = 0.f;
  __syncthreads();
  if (tid < KNN*NA) {
    int k = tid / NA, a = tid % NA;
    float s = (dk[k][0]*dirs[a*3] + dk[k][1]*dirs[a*3+1]) + dk[k][2]*dirs[a*3+2];
    th[tid] = fmaxf(s, 0.f);
  }
  __syncthreads();
  int quarter = co*NA/4;
  uint2* dst = (uint2*)(out + (size_t)bq*co*NA);
  const uint2* gb = (const uint2*)(g + (size_t)b*npts*co*NA);
  for (int t4 = tid; t4 < quarter; t4 += 256) {
    int a = (4*t4) % NA;          // 0, 4, or 8 — quad never straddles an o-row
    const float* tha = th + a;
    float m0=-3.0e38f, m1=-3.0e38f, m2=-3.0e38f, m3=-3.0e38f;
    #pragma unroll 5
    for (int k = 0; k < KNN; ++k) {
      uint2 pv = gb[(size_t)nb[k]*quarter + t4];
      float4 tv = *(const float4*)(tha + k*NA);   // 16B-aligned: a%4==0, 48|k*NA*4
      m0 = fmaxf(m0, tv.x*b2f((u16)(pv.x)));
      m1 = fmaxf(m1, tv.y*b2f((u16)(pv.x >> 16)));
      m2 = fmaxf(m2, tv.z*b2f((u16)(pv.y)));
      m3 = fmaxf(m3, tv.w*b2f((u16)(pv.y >> 16)));
    }
    uint2 d = dst[t4];
    float v0 = b2f((u16)d.x) + m0;
    float v1 = b2f((u16)(d.x >> 16)) + m1;
    float v2 = b2f((u16)d.y) + m2;
    float v3 = b2f((u16)(d.y >> 16)) + m3;
    uint2 r; r.x = packb(v0, v1); r.y = packb(v2, v3);
    dst[t4] = r;
    int ch = t4 / 3;              // NA/4 = 3 quads per channel
    atomicAdd(&sstat[0][ch], (v0 + v1) + (v2 + v3));
    atomicAdd(&sstat[1][ch], (v0*v0 + v1*v1) + (v2*v2 + v3*v3));
  }
  __syncthreads();
  if (tid < co) {
    float* pg = part + (size_t)(bq & (BNG-1))*2*co;
    atomicAdd(&pg[tid], sstat[0][tid]);
    atomicAdd(&pg[co + tid], sstat[1][tid]);
  }
}

// ---------------- layer4: fsmax + fea_of fused, channel-split, vectorized ----------------
template<int SPL>
__global__ __launch_bounds__(256) void eq_fsmax_fea(
    const u16* __restrict__ g, const float* __restrict__ fcin,
    const float4* __restrict__ vf, const float* __restrict__ dirs,
    const int* __restrict__ idx, float* __restrict__ outfea,
    int npts, int co) {
  constexpr int CHUNK = C4 / SPL;
  int part = blockIdx.x % SPL;
  int bq = blockIdx.x / SPL;
  int b = bq / npts;
  __shared__ float th[KNN*NA];
  __shared__ float dk[KNN][3];
  __shared__ int nb[KNN];
  __shared__ float row[CHUNK*NA];
  int tid = threadIdx.x;
  if (tid < KNN) {
    int m = idx[(size_t)bq*KNN + tid];
    nb[tid] = m;
    float4 vq = vf[bq];
    float4 vm = vf[(size_t)b*npts + m];
    float dx = vm.x - vq.x, dy = vm.y - vq.y, dz = vm.z - vq.z;
    float nrm = sqrtf((dx*dx + dy*dy) + dz*dz) + 1e-8f;
    dk[tid][0] = dx/nrm; dk[tid][1] = dy/nrm; dk[tid][2] = dz/nrm;
  }
  __syncthreads();
  if (tid < KNN*NA) {
    int k = tid / NA, a = tid % NA;
    float s = (dk[k][0]*dirs[a*3] + dk[k][1]*dirs[a*3+1]) + dk[k][2]*dirs[a*3+2];
    th[tid] = fmaxf(s, 0.f);
  }
  __syncthreads();
  int o0 = part * CHUNK;
  const float4* fcr = (const float4*)(fcin + ((size_t)bq*co + o0)*NA);
  const uint2* gb = (const uint2*)(g + (size_t)b*npts*co*NA + (size_t)o0*NA);
  int gquarter = co*NA/4;
  for (int t4 = tid; t4 < CHUNK*NA/4; t4 += 256) {
    int a = (4*t4) % NA;
    const float* tha = th + a;
    float m0=-3.0e38f, m1=-3.0e38f, m2=-3.0e38f, m3=-3.0e38f;
    #pragma unroll 5
    for (int k = 0; k < KNN; ++k) {
      uint2 pv = gb[(size_t)nb[k]*gquarter + t4];
      float4 tv = *(const float4*)(tha + k*NA);
      m0 = fmaxf(m0, tv.x*b2f((u16)(pv.x)));
      m1 = fmaxf(m1, tv.y*b2f((u16)(pv.x >> 16)));
      m2 = fmaxf(m2, tv.z*b2f((u16)(pv.y)));
      m3 = fmaxf(m3, tv.w*b2f((u16)(pv.y >> 16)));
    }
    float4 fc4 = fcr[t4];
    row[4*t4+0] = fc4.x + m0;
    row[4*t4+1] = fc4.y + m1;
    row[4*t4+2] = fc4.z + m2;
    row[4*t4+3] = fc4.w + m3;
  }
  __syncthreads();
  for (int o = tid; o < CHUNK; o += 256) {
    float m = row[o*NA];
    #pragma unroll
    for (int a = 1; a < NA; ++a) m = fmaxf(m, row[o*NA + a]);
    outfea[(size_t)bq*co + o0 + o] = m;
  }
}

// ---------------- normalize + relu (in place) + fea_of (folds BNG partials) ----------------
// (layer2 only: fm2 post-BN is consumed by linear3, so the in-place write is required)
__global__ __launch_bounds__(256) void eq_bnrelu_fea(
    u16* __restrict__ fm, const float* __restrict__ part,
    const float* __restrict__ gamma, const float* __restrict__ beta,
    float* __restrict__ outfea, int npts, int co) {
  int bq = blockIdx.x;
  int tid = threadIdx.x;
  __shared__ float sc[C3], sh[C3];
  __shared__ float row[C3*NA];
  for (int o = tid; o < co; o += 256) {
    float s = 0.f, s2 = 0.f;
    for (int g = 0; g < BNG; ++g) {
      s  += part[(size_t)g*2*co + o];
      s2 += part[(size_t)g*2*co + co + o];
    }
    float cnt = (float)(Bz*npts*NA);
    float mean = s / cnt;
    float var = fmaxf(s2 / cnt - mean*mean, 0.f);
    float inv = 1.0f / sqrtf(var + 1e-5f);
    sc[o] = gamma[o] * inv;
    sh[o] = beta[o] - mean * gamma[o] * inv;
  }
  __syncthreads();
  uint2* p = (uint2*)(fm + (size_t)bq*co*NA);
  int quarter = co*NA/4;
  for (int t4 = tid; t4 < quarter; t4 += 256) {
    int o = (4*t4) / NA;            // quad never straddles o-row
    float s = sc[o], h = sh[o];
    uint2 pv = p[t4];
    float v0 = fmaxf(b2f((u16)pv.x)*s + h, 0.f);
    float v1 = fmaxf(b2f((u16)(pv.x >> 16))*s + h, 0.f);
    float v2 = fmaxf(b2f((u16)pv.y)*s + h, 0.f);
    float v3 = fmaxf(b2f((u16)(pv.y >> 16))*s + h, 0.f);
    uint2 r; r.x = packb(v0, v1); r.y = packb(v2, v3);
    p[t4] = r;
    row[4*t4+0] = v0; row[4*t4+1] = v1; row[4*t4+2] = v2; row[4*t4+3] = v3;
  }
  __syncthreads();
  for (int o = tid; o < co; o += 256) {
    float m = row[o*NA];
    #pragma unroll
    for (int a = 1; a < NA; ++a) m = fmaxf(m, row[o*NA + a]);
    outfea[(size_t)bq*co + o] = m;
  }
}

// ---------------- fused BN+relu+fea+pool (layers 1 & 3: fm post-BN has no other consumer) ----
__global__ __launch_bounds__(256) void eq_bnfea_pool(
    const u16* __restrict__ fm, const float* __restrict__ part,
    const float* __restrict__ gamma, const float* __restrict__ beta,
    const int* __restrict__ idx, float* __restrict__ outfea,
    u16* __restrict__ fmp, int npts, int co) {
  int bq = blockIdx.x;
  int b = bq / npts, q = bq % npts;
  int tid = threadIdx.x;
  __shared__ float sc[C3], sh[C3];
  __shared__ float row[C3*NA];
  __shared__ int nb[4];
  for (int o = tid; o < co; o += 256) {
    float s = 0.f, s2 = 0.f;
    for (int g = 0; g < BNG; ++g) {
      s  += part[(size_t)g*2*co + o];
      s2 += part[(size_t)g*2*co + co + o];
    }
    float cnt = (float)(Bz*npts*NA);
    float mean = s / cnt;
    float var = fmaxf(s2 / cnt - mean*mean, 0.f);
    float inv = 1.0f / sqrtf(var + 1e-5f);
    sc[o] = gamma[o] * inv;
    sh[o] = beta[o] - mean * gamma[o] * inv;
  }
  bool do_pool = ((q & 3) == 0);       // POOL_RATE = 4
  if (do_pool && tid < 4) nb[tid] = idx[(size_t)bq*KNN + tid];  // POOL_K = 4 nearest
  __syncthreads();
  int quarter = co*NA/4;
  const uint2* own = (const uint2*)(fm + (size_t)bq*co*NA);
  const uint2* base = (const uint2*)(fm + (size_t)b*npts*co*NA);
  uint2* dst = (uint2*)(fmp + ((size_t)b*(npts/4) + (q >> 2))*co*NA);
  for (int t4 = tid; t4 < quarter; t4 += 256) {
    int o = (4*t4) / NA;               // quad never straddles o-row
    float s = sc[o], h = sh[o];
    uint2 pv = own[t4];
    float v0 = fmaxf(b2f((u16)pv.x)*s + h, 0.f);
    float v1 = fmaxf(b2f((u16)(pv.x >> 16))*s + h, 0.f);
    float v2 = fmaxf(b2f((u16)pv.y)*s + h, 0.f);
    float v3 = fmaxf(b2f((u16)(pv.y >> 16))*s + h, 0.f);
    row[4*t4+0] = v0; row[4*t4+1] = v1; row[4*t4+2] = v2; row[4*t4+3] = v3;
    if (do_pool) {
      float m0=v0, m1=v1, m2=v2, m3=v3;
      #pragma unroll
      for (int kk = 0; kk < 4; ++kk) {
        uint2 w = base[(size_t)nb[kk]*quarter + t4];
        m0 = fmaxf(m0, fmaxf(b2f((u16)w.x)*s + h, 0.f));
        m1 = fmaxf(m1, fmaxf(b2f((u16)(w.x >> 16))*s + h, 0.f));
        m2 = fmaxf(m2, fmaxf(b2f((u16)w.y)*s + h, 0.f));
        m3 = fmaxf(m3, fmaxf(b2f((u16)(w.y >> 16))*s + h, 0.f));
      }
      uint2 r; r.x = packb(m0, m1); r.y = packb(m2, m3);
      dst[t4] = r;
    }
  }
  __syncthreads();
  for (int o = tid; o < co; o += 256) {
    float m = row[o*NA];
    #pragma unroll
    for (int a = 1; a < NA; ++a) m = fmaxf(m, row[o*NA + a]);
    outfea[(size_t)bq*co + o] = m;
  }
}

// ---------------- host orchestration ----------------
extern "C" void kernel_launch(void* const* d_in, const int* in_sizes, int n_in,
                              void* d_out, int out_size, void* d_ws, size_t ws_size,
                              hipStream_t stream) {
  float* ws = (float*)d_ws;
  float* out = (float*)d_out;
  u16* arena = (u16*)(ws + OFF_HALF);

  InPtrs ip;
  for (int i = 0; i < 24; ++i) ip.p[i] = d_in[i];

  float4* v0f = (float4*)(ws + OFF_V0F);
  float4* v1f = (float4*)(ws + OFF_V1F);
  float4* v2f = (float4*)(ws + OFF_V2F);
  int* idx0 = (int*)(ws + OFF_IDX0);
  int* idx1 = (int*)(ws + OFF_IDX1);
  int* idx2 = (int*)(ws + OFF_IDX2);
  u16* bufA = arena + HA;            // fm0 -> fm2
  u16* bufB = arena + HB;            // fm1 -> fm3 (RAW pre-BN)
  float* fc4f = (float*)(arena + HB);// layer4 fc carrier (fm3 dead by then)
  u16* bufG = arena + HG;            // g (Ws-transformed)
  u16* bufP = arena + HP;            // fmp1/fmp2 (upper half of G)
  u16* wch = arena + WTO;            // Wc split-bf16 transposed hi
  u16* wcl = wch + 174080;           // Wc lo
  u16* wsh = wcl + 174080;           // Ws hi
  u16* wsl = wsh + 174080;           // Ws lo
  float* partA = ws + OFF_PART;            // 32 x 2*C1
  float* partB = ws + OFF_PART + 4096;     // 32 x 2*C2
  float* partC = ws + OFF_PART + 12288;    // 32 x 2*C3
  const float* DIRS = ws + OFF_DIRS;

  // 0) convert all inputs; then split+transpose weights for MFMA
  {
    int total = Bz*N0 + 351312 + (int)PART_SZ;
    eq_convert_all<<<(total + 255)/256, 256, 0, stream>>>(ip, ws);
  }
  eq_wprep<<<(174080 + 255)/256, 256, 0, stream>>>(ws, wch, wcl, wsh, wsl);

  // 1) all 3 KNN levels in one dispatch
  eq_knn_all<<<Bz*N0/4 + Bz*N1/4 + Bz*N2/4, 256, 0, stream>>>(v0f, idx0, v1f, idx1, v2f, idx2);
  eq_conv_surface<<<Bz*N0, 128, 0, stream>>>(v0f, idx0, ws + OFF_K0F, bufA, out + OUT0);

  // 2) layer1: fm0(bufA,C0) -> fm1(bufB,C1) at N0; fused BN+fea+pool1 -> out1 + fmp1
  eq_linear_mfma<C0, C1, 8, 1, u16><<<(Bz*N0/8)*2*1, 256, 0, stream>>>(
      bufA, wch + 0, wcl + 0, wsh + 0, wsl + 0, ws + OFF_BC + 0, bufB, bufG);
  eq_fsmax<<<Bz*N0, 256, 0, stream>>>(bufG, v0f, DIRS + 0, idx0, bufB, partA, N0, C1);
  eq_bnfea_pool<<<Bz*N0, 256, 0, stream>>>(bufB, partA, ws + OFF_BN + 0, ws + OFF_BN + 64,
                                           idx0, out + OUT1, bufP, N0, C1);

  // 3) layer2: fmp1(bufP,C1) -> fm2(bufA,C2) at N1 (in-place BN kept: linear3 reads fm2)
  eq_linear_mfma<C1, C2, 8, 2, u16><<<(Bz*N1/8)*2*2, 256, 0, stream>>>(
      bufP, wch + 2048, wcl + 2048, wsh + 2048, wsl + 2048, ws + OFF_BC + 64, bufA, bufG);
  eq_fsmax<<<Bz*N1, 256, 0, stream>>>(bufG, v1f, DIRS + 36, idx1, bufA, partB, N1, C2);
  eq_bnrelu_fea<<<Bz*N1, 256, 0, stream>>>(bufA, partB, ws + OFF_BN + 128, ws + OFF_BN + 256,
                                           out + OUT2, N1, C2);

  // 4) layer3: fm2(bufA,C2) -> fm3(bufB,C3) at N1; fused BN+fea+pool2 -> out3 + fmp2
  eq_linear_mfma<C2, C3, 8, 4, u16><<<(Bz*N1/8)*2*4, 256, 0, stream>>>(
      bufA, wch + 10240, wcl + 10240, wsh + 10240, wsl + 10240, ws + OFF_BC + 192, bufB, bufG);
  eq_fsmax<<<Bz*N1, 256, 0, stream>>>(bufG, v1f, DIRS + 72, idx1, bufB, partC, N1, C3);
  eq_bnfea_pool<<<Bz*N1, 256, 0, stream>>>(bufB, partC, ws + OFF_BN + 384, ws + OFF_BN + 640,
                                           idx1, out + OUT3, bufP, N1, C3);

  // 5) layer4: fmp2(bufP,C3) -> fc4(f32) + g; fused fsmax+fea (4-way split) -> out4
  eq_linear_mfma<C3, C4, 4, 8, float><<<(Bz*N2/4)*2*8, 256, 0, stream>>>(
      bufP, wch + 43008, wcl + 43008, wsh + 43008, wsl + 43008, ws + OFF_BC + 448, fc4f, bufG);
  eq_fsmax_fea<4><<<Bz*N2*4, 256, 0, stream>>>(bufG, fc4f, v2f, DIRS + 108, idx2, out + OUT4, N2, C4);
}

// Round 12
// 407.026 us; speedup vs baseline: 1.1762x; 1.0136x over previous
//
#include <hip/hip_runtime.h>
#include <hip/hip_bf16.h>
#include <math.h>

typedef unsigned short u16;
typedef unsigned long long u64;
#define DEV static __device__ __forceinline__

// ---------------- problem constants ----------------
constexpr int Bz = 2, N0 = 4096, N1 = 1024, N2 = 256, KNN = 20, NA = 12;
constexpr int C0 = 32, C1 = 64, C2 = 128, C3 = 256, C4 = 512;
constexpr int BNG = 32;  // batchnorm atomic groups

// ---------------- workspace layout ----------------
constexpr size_t OFF_V0F   = 0;                       // Bz*N0 float4 (w = |p|^2)
constexpr size_t OFF_V1F   = 32768;
constexpr size_t OFF_V2F   = 40960;
constexpr size_t OFF_K0F   = 43008;                   // 1152
constexpr size_t OFF_DIRS  = 44160;                   // 144
constexpr size_t OFF_WC    = 44304;                   // 174080
constexpr size_t OFF_WS    = 218384;                  // 174080
constexpr size_t OFF_BC    = 392464;                  // 960
constexpr size_t OFF_BN    = 393424;                  // 896
constexpr size_t OFF_FLAG  = 394832;                  // 16 (unused now)
constexpr size_t OFF_IDX0  = 394848;                  // 163840 ints
constexpr size_t OFF_IDX1  = 558688;                  // 40960
constexpr size_t OFF_IDX2  = 599648;                  // 10240
constexpr size_t OFF_PART  = 609888;                  // 28672 floats
constexpr size_t PART_SZ   = 28672;
constexpr size_t OFF_HALF  = OFF_PART + PART_SZ;      // u16 arena base (float offset)

constexpr size_t HA = 0;                              // fm0/fm2
constexpr size_t HB = 3145728;                        // fm1/fm3 ; layer4: fc4 as f32
constexpr size_t HG = 9437184;                        // g1..g4
constexpr size_t HP = HG + 3145728;                   // fmp1/fmp2 (upper half of G)
constexpr size_t WTO = 15728640;                      // W split-bf16 transposed (past G high-water)

// output element offsets (float32)
constexpr size_t OUT0 = 0;
constexpr size_t OUT1 = OUT0 + (size_t)Bz*N0*C0;
constexpr size_t OUT2 = OUT1 + (size_t)Bz*N0*C1;
constexpr size_t OUT3 = OUT2 + (size_t)Bz*N1*C2;
constexpr size_t OUT4 = OUT3 + (size_t)Bz*N1*C3;

DEV float b2f(u16 v) { return __uint_as_float(((unsigned int)v) << 16); }
DEV u16 f2b(float f) {
  unsigned int u = __float_as_uint(f);
  unsigned int lsb = (u >> 16) & 1u;
  return (u16)((u + 0x7fffu + lsb) >> 16);
}
DEV unsigned packb(float a, float b) {
  return (unsigned)f2b(a) | ((unsigned)f2b(b) << 16);
}

DEV u64 shflx64(u64 v, int m) {
  int lo = __shfl_xor((int)(unsigned)v, m, 64);
  int hi = __shfl_xor((int)(unsigned)(v >> 32), m, 64);
  return ((u64)(unsigned)hi << 32) | (unsigned)lo;
}
DEV int mbcnt64(u64 m) {
  return __builtin_amdgcn_mbcnt_hi((unsigned)(m >> 32),
         __builtin_amdgcn_mbcnt_lo((unsigned)m, 0));
}

DEV void st12(float* dst, const float* v) {
  float4 a{v[0],v[1],v[2],v[3]}, b{v[4],v[5],v[6],v[7]}, c{v[8],v[9],v[10],v[11]};
  ((float4*)dst)[0] = a; ((float4*)dst)[1] = b; ((float4*)dst)[2] = c;
}
DEV void st12(u16* dst, const float* v) {
  uint2 a{packb(v[0],v[1]), packb(v[2],v[3])};
  uint2 b{packb(v[4],v[5]), packb(v[6],v[7])};
  uint2 c{packb(v[8],v[9]), packb(v[10],v[11])};
  ((uint2*)dst)[0] = a; ((uint2*)dst)[1] = b; ((uint2*)dst)[2] = c;
}

// ---------------- convert all inputs -> f32 (self dtype-detect, zero partials) ----------------
struct InPtrs { const void* p[24]; };

__global__ void eq_convert_all(InPtrs in, float* ws) {
  __shared__ int sflag;
  {
    const u16* v = (const u16*)in.p[0];
    if (threadIdx.x < 64) {
      int bad = 0;
      #pragma unroll
      for (int j = 0; j < 4; ++j) {
        unsigned u = v[threadIdx.x*4 + j];
        int ex = (u >> 7) & 0xFF;
        bad += (((u & 0x7FFFu) != 0u) && (ex < 64 || ex > 191)) ? 1 : 0;
      }
      int tot = bad;
      #pragma unroll
      for (int s = 32; s > 0; s >>= 1) tot += __shfl_xor(tot, s, 64);
      if (threadIdx.x == 0) sflag = (tot >= 8) ? 1 : 0;   // 1 => inputs are f32
    }
    __syncthreads();
  }
  int f32mode = sflag;
  int t = blockIdx.x * blockDim.x + threadIdx.x;
  if (t < Bz*N0) {      // one thread per point; w = |p|^2
    float x, y, z;
    if (f32mode) { const float* v = (const float*)in.p[0]; x=v[t*3]; y=v[t*3+1]; z=v[t*3+2]; }
    else { const u16* v = (const u16*)in.p[0]; x=b2f(v[t*3]); y=b2f(v[t*3+1]); z=b2f(v[t*3+2]); }
    float4 o; o.x=x; o.y=y; o.z=z; o.w=(x*x + y*y) + z*z;
    ((float4*)(ws + OFF_V0F))[t] = o;
    int b = t / N0, i = t % N0;
    if ((i & 3) == 0)  ((float4*)(ws + OFF_V1F))[b*N1 + (i >> 2)] = o;
    if ((i & 15) == 0) ((float4*)(ws + OFF_V2F))[b*N2 + (i >> 4)] = o;
    return;
  }
  int r = t - Bz*N0;
  if (r >= 351312) {    // tail range zeroes bn partials
    int z = r - 351312;
    if (z < (int)PART_SZ) ws[OFF_PART + z] = 0.f;
    return;
  }
  const int cnt[23] = {1152, 36,2048,64,2048, 36,8192,128,8192,
                       36,32768,256,32768, 36,131072,512,131072,
                       64,64,128,128,256,256};
  const size_t off[23] = {OFF_K0F,
    OFF_DIRS+0,   OFF_WC+0,     OFF_BC+0,   OFF_WS+0,
    OFF_DIRS+36,  OFF_WC+2048,  OFF_BC+64,  OFF_WS+2048,
    OFF_DIRS+72,  OFF_WC+10240, OFF_BC+192, OFF_WS+10240,
    OFF_DIRS+108, OFF_WC+43008, OFF_BC+448, OFF_WS+43008,
    OFF_BN+0, OFF_BN+64, OFF_BN+128, OFF_BN+256, OFF_BN+384, OFF_BN+640};
  for (int i = 0; i < 23; ++i) {
    if (r < cnt[i]) {
      float val = f32mode ? ((const float*)in.p[i+1])[r] : b2f(((const u16*)in.p[i+1])[r]);
      ws[off[i] + r] = val;
      return;
    }
    r -= cnt[i];
  }
}

// ---------------- W prep: split-bf16 (hi+lo), transposed to [CO][CI] per layer --------------
__global__ void eq_wprep(const float* __restrict__ ws,
    u16* __restrict__ ch, u16* __restrict__ cl,
    u16* __restrict__ sh, u16* __restrict__ sl) {
  int e = blockIdx.x*256 + threadIdx.x;
  if (e >= 174080) return;
  const int co[4] = {64,128,256,512};
  const int ci[4] = {32,64,128,256};
  const int off[4] = {0,2048,10240,43008};
  int li = 0, loc = e;
  if (e >= 43008) { li = 3; loc = e - 43008; }
  else if (e >= 10240) { li = 2; loc = e - 10240; }
  else if (e >= 2048) { li = 1; loc = e - 2048; }
  int c = loc / co[li], o = loc % co[li];
  size_t dst = (size_t)off[li] + (size_t)o*ci[li] + c;
  float wc = ws[OFF_WC + e];
  u16 h = f2b(wc); u16 l = f2b(wc - b2f(h));
  ch[dst] = h; cl[dst] = l;
  float wv = ws[OFF_WS + e];
  h = f2b(wv); l = f2b(wv - b2f(h));
  sh[dst] = h; sl[dst] = l;
}

// ---------------- KNN v10: 16-bit coarse radix + exact rank-select ----------------
DEV unsigned cand_ud(const float4 vq, const float4 vc) {
  float dt = fmaf(vq.x, vc.x, fmaf(vq.y, vc.y, vq.z*vc.z));
  float d  = fmaf(-2.0f, dt, vq.w + vc.w);
  unsigned u = __float_as_uint(d);
  return u ^ ((unsigned)(((int)u) >> 31) | 0x80000000u);
}

#define INSA(u,c) do { bool lt1=(u)<dA1, lt2=(u)<dA2, lt3=(u)<dA3, lt4=(u)<dA4; \
  dA4=lt3?dA3:(lt4?(u):dA4); iA4=lt3?iA3:(lt4?(c):iA4); \
  dA3=lt2?dA2:(lt3?(u):dA3); iA3=lt2?iA2:(lt3?(c):iA3); \
  dA2=lt1?dA1:(lt2?(u):dA2); iA2=lt1?iA1:(lt2?(c):iA2); \
  dA1=lt1?(u):dA1;           iA1=lt1?(c):iA1; } while(0)
#define INSB(u,c) do { bool lt1=(u)<dB1, lt2=(u)<dB2, lt3=(u)<dB3, lt4=(u)<dB4; \
  dB4=lt3?dB3:(lt4?(u):dB4); iB4=lt3?iB3:(lt4?(c):iB4); \
  dB3=lt2?dB2:(lt3?(u):dB3); iB3=lt2?iB2:(lt3?(c):iB3); \
  dB2=lt1?dB1:(lt2?(u):dB2); iB2=lt1?iB1:(lt2?(c):iB2); \
  dB1=lt1?(u):dB1;           iB1=lt1?(c):iB1; } while(0)

#define CMP1(uu,cc) do { bool sel=(uu)<=p; u64 m=__ballot(sel); \
  int pos = base2 + mbcnt64(m); \
  if (sel && pos < 128) selw[pos] = ((u64)(uu) << 32) | (unsigned)(cc); \
  base2 += __popcll(m); } while(0)

template<int NPTS>
DEV void knn_body(int blk, const float4* __restrict__ vf, int* __restrict__ idx_out,
                  char* smem) {
  constexpr int CPL = NPTS/64;       // candidates per lane
  constexpr int HC  = CPL/2;         // candidates per network
  int wave = threadIdx.x >> 6, lane = threadIdx.x & 63;
  u64* selw = (u64*)smem + wave*128;
  int* extrw = (int*)(smem + 4*128*8) + wave*24;
  int qid = blk*4 + wave;
  int b = qid / NPTS, q = qid % NPTS;
  const float4* vb = vf + (size_t)b*NPTS;
  float4 vq = vb[q];

  unsigned dA1=~0u,dA2=~0u,dA3=~0u,dA4=~0u; int iA1=0,iA2=0,iA3=0,iA4=0;
  unsigned dB1=~0u,dB2=~0u,dB3=~0u,dB4=~0u; int iB1=0,iB2=0,iB3=0,iB4=0;

  if (CPL >= 8) {
    for (int jb = 0; jb < CPL; jb += 8) {
      int base = jb*64 + lane;
      float4 c0 = vb[base];
      float4 c1 = vb[base + 64];
      float4 c2 = vb[base + 128];
      float4 c3 = vb[base + 192];
      float4 c4 = vb[base + 256];
      float4 c5 = vb[base + 320];
      float4 c6 = vb[base + 384];
      float4 c7 = vb[base + 448];
      unsigned u0 = cand_ud(vq, c0);
      unsigned u1 = cand_ud(vq, c1);
      unsigned u2 = cand_ud(vq, c2);
      unsigned u3 = cand_ud(vq, c3);
      unsigned u4 = cand_ud(vq, c4);
      unsigned u5 = cand_ud(vq, c5);
      unsigned u6 = cand_ud(vq, c6);
      unsigned u7 = cand_ud(vq, c7);
      INSA(u0, base);       INSB(u1, base + 64);
      INSA(u2, base + 128); INSB(u3, base + 192);
      INSA(u4, base + 256); INSB(u5, base + 320);
      INSA(u6, base + 384); INSB(u7, base + 448);
    }
  } else {
    int base = lane;
    float4 c0 = vb[base];
    float4 c1 = vb[base + 64];
    float4 c2 = vb[base + 128];
    float4 c3 = vb[base + 192];
    unsigned u0 = cand_ud(vq, c0);
    unsigned u1 = cand_ud(vq, c1);
    unsigned u2 = cand_ud(vq, c2);
    unsigned u3 = cand_ud(vq, c3);
    INSA(u0, base);       INSB(u1, base + 64);
    INSA(u2, base + 128); INSB(u3, base + 192);
  }

  // ---- coarse 16-bit radix select: exact 21st-smallest HIGH-16 bucket p16.
  // true 21st distance has (ud>>16) <= p16, so p = (p16<<16)|0xFFFF keeps the
  // exact-superset property; exact u64 rank-select downstream => same output.
  unsigned hA1 = dA1 >> 16, hA2 = dA2 >> 16, hA3 = dA3 >> 16, hA4 = dA4 >> 16;
  unsigned hB1 = dB1 >> 16, hB2 = dB2 >> 16, hB3 = dB3 >> 16, hB4 = dB4 >> 16;
  unsigned p16 = 0;
  for (int bit = 15; bit >= 0; --bit) {
    unsigned T = p16 | (1u << bit);
    int cnt = __popcll(__ballot(hA1 < T)) + __popcll(__ballot(hA2 < T))
            + __popcll(__ballot(hA3 < T)) + __popcll(__ballot(hA4 < T))
            + __popcll(__ballot(hB1 < T)) + __popcll(__ballot(hB2 < T))
            + __popcll(__ballot(hB3 < T)) + __popcll(__ballot(hB4 < T));
    if (cnt < KNN+1) p16 = T;
  }
  unsigned p = (p16 << 16) | 0xFFFFu;
  size_t obase = (size_t)qid*KNN;
  bool need_fb = (HC > 4) &&
                 ((__ballot(dA4 <= p) | __ballot(dB4 <= p)) != 0ULL);

  if (!need_fb) {
    bool pA1=dA1<=p, pA2=dA2<=p, pA3=dA3<=p, pA4=dA4<=p;
    bool pB1=dB1<=p, pB2=dB2<=p, pB3=dB3<=p, pB4=dB4<=p;
    u64 m1=__ballot(pA1), m2=__ballot(pA2), m3=__ballot(pA3), m4=__ballot(pA4);
    u64 m5=__ballot(pB1), m6=__ballot(pB2), m7=__ballot(pB3), m8=__ballot(pB4);
    int c1=__popcll(m1), c2=__popcll(m2), c3=__popcll(m3), c4=__popcll(m4);
    int c5=__popcll(m5), c6=__popcll(m6), c7=__popcll(m7), c8=__popcll(m8);
    int S = ((c1+c2)+(c3+c4)) + ((c5+c6)+(c7+c8));
    if (S > 127) need_fb = true;
    else {
      int o1=c1, o2=o1+c2, o3=o2+c3, o4=o3+c4, o5=o4+c5, o6=o5+c6, o7=o6+c7;
      if (pA1) selw[mbcnt64(m1)]      = ((u64)dA1 << 32) | (unsigned)iA1;
      if (pA2) selw[o1 + mbcnt64(m2)] = ((u64)dA2 << 32) | (unsigned)iA2;
      if (pA3) selw[o2 + mbcnt64(m3)] = ((u64)dA3 << 32) | (unsigned)iA3;
      if (pA4) selw[o3 + mbcnt64(m4)] = ((u64)dA4 << 32) | (unsigned)iA4;
      if (pB1) selw[o4 + mbcnt64(m5)] = ((u64)dB1 << 32) | (unsigned)iB1;
      if (pB2) selw[o5 + mbcnt64(m6)] = ((u64)dB2 << 32) | (unsigned)iB2;
      if (pB3) selw[o6 + mbcnt64(m7)] = ((u64)dB3 << 32) | (unsigned)iB3;
      if (pB4) selw[o7 + mbcnt64(m8)] = ((u64)dB4 << 32) | (unsigned)iB4;
      for (int sl = lane; sl < S; sl += 64) {
        u64 mykey = selw[sl];
        int rank = 0;
        for (int j2 = 0; j2 < S; ++j2) rank += (selw[j2] < mykey) ? 1 : 0;
        if (rank >= 1 && rank <= KNN)     // rank 0 = self
          idx_out[obase + rank - 1] = (int)(unsigned)(mykey & 0xFFFFFFFFu);
      }
    }
  }
  if (need_fb && CPL >= 8) {
    int base2 = 0;
    for (int jb = 0; jb < CPL; jb += 8) {
      int bidx = jb*64 + lane;
      float4 c0 = vb[bidx];
      float4 c1 = vb[bidx + 64];
      float4 c2 = vb[bidx + 128];
      float4 c3 = vb[bidx + 192];
      float4 c4 = vb[bidx + 256];
      float4 c5 = vb[bidx + 320];
      float4 c6 = vb[bidx + 384];
      float4 c7 = vb[bidx + 448];
      unsigned u0 = cand_ud(vq, c0);
      unsigned u1 = cand_ud(vq, c1);
      unsigned u2 = cand_ud(vq, c2);
      unsigned u3 = cand_ud(vq, c3);
      unsigned u4 = cand_ud(vq, c4);
      unsigned u5 = cand_ud(vq, c5);
      unsigned u6 = cand_ud(vq, c6);
      unsigned u7 = cand_ud(vq, c7);
      CMP1(u0, bidx);       CMP1(u1, bidx + 64);
      CMP1(u2, bidx + 128); CMP1(u3, bidx + 192);
      CMP1(u4, bidx + 256); CMP1(u5, bidx + 320);
      CMP1(u6, bidx + 384); CMP1(u7, bidx + 448);
    }
    if (base2 <= 127) {
      int S = base2;
      for (int sl = lane; sl < S; sl += 64) {
        u64 mykey = selw[sl];
        int rank = 0;
        for (int j2 = 0; j2 < S; ++j2) rank += (selw[j2] < mykey) ? 1 : 0;
        if (rank >= 1 && rank <= KNN)
          idx_out[obase + rank - 1] = (int)(unsigned)(mykey & 0xFFFFFFFFu);
      }
    } else {
      const u64 KINF = ~0ULL;
      u64 K1=KINF, K2=KINF, K3=KINF, K4=KINF;
      for (int j = 0; j < CPL; ++j) {
        int c = j*64 + lane;
        u64 k = ((u64)cand_ud(vq, vb[c]) << 32) | (unsigned)c;
        bool lt1 = k < K1, lt2 = k < K2, lt3 = k < K3, lt4 = k < K4;
        K4 = lt3 ? K3 : (lt4 ? k : K4);
        K3 = lt2 ? K2 : (lt3 ? k : K3);
        K2 = lt1 ? K1 : (lt2 ? k : K2);
        K1 = lt1 ? k  : K1;
      }
      for (int r = 0; r < KNN+1; ++r) {
        u64 g = K1;
        #pragma unroll
        for (int s = 32; s; s >>= 1) { u64 o = shflx64(g, s); g = (o < g) ? o : g; }
        int gidx = (int)(unsigned)(g & 0xFFFFFFFFu);
        if (lane == 0) {
          extrw[r] = gidx;
          if (r > 0) idx_out[obase + r - 1] = gidx;
        }
        if (r < KNN && lane == (gidx & 63)) {
          K1 = K2; K2 = K3; K3 = K4; K4 = KINF;
          if (K1 == KINF) {
            for (int j = 0; j < CPL; ++j) {
              int c = j*64 + lane;
              u64 k = ((u64)cand_ud(vq, vb[c]) << 32) | (unsigned)c;
              bool ex = false;
              for (int e = 0; e <= r; ++e) ex |= (extrw[e] == c);
              if (!ex) {
                bool lt1 = k < K1, lt2 = k < K2, lt3 = k < K3, lt4 = k < K4;
                K4 = lt3 ? K3 : (lt4 ? k : K4);
                K3 = lt2 ? K2 : (lt3 ? k : K3);
                K2 = lt1 ? K1 : (lt2 ? k : K2);
                K1 = lt1 ? k  : K1;
              }
            }
          }
        }
      }
    }
  }
}

// ---------------- fused KNN: all 3 levels in one dispatch ----------------
__global__ __launch_bounds__(256) void eq_knn_all(
    const float4* __restrict__ v0, int* __restrict__ i0,
    const float4* __restrict__ v1, int* __restrict__ i1,
    const float4* __restrict__ v2, int* __restrict__ i2) {
  __shared__ __align__(16) char smem[4*128*8 + 4*24*4];
  int blk = blockIdx.x;
  constexpr int NB0 = Bz*N0/4, NB1 = Bz*N1/4;
  if (blk < NB0)            knn_body<N0>(blk, v0, i0, smem);
  else if (blk < NB0+NB1)   knn_body<N1>(blk - NB0, v1, i1, smem);
  else                      knn_body<N2>(blk - NB0 - NB1, v2, i2, smem);
}

// ---------------- conv_surface + relu + fea_of(fm0), vectorized stores ----------------
__global__ __launch_bounds__(128) void eq_conv_surface(
    const float4* __restrict__ v0f, const int* __restrict__ idx0,
    const float* __restrict__ K0f, u16* __restrict__ fm0, float* __restrict__ out0) {
  int bq = blockIdx.x;          // b*N0 + q
  int b = bq >> 12;
  __shared__ float dk[KNN][3];
  __shared__ float row[C0*NA];
  int tid = threadIdx.x;
  if (tid < KNN) {
    int m = idx0[(size_t)bq*KNN + tid];
    float4 vq = v0f[bq];
    float4 vm = v0f[(size_t)b*N0 + m];
    float dx = vm.x - vq.x, dy = vm.y - vq.y, dz = vm.z - vq.z;
    float nrm = sqrtf((dx*dx + dy*dy) + dz*dz) + 1e-8f;
    dk[tid][0] = dx/nrm; dk[tid][1] = dy/nrm; dk[tid][2] = dz/nrm;
  }
  __syncthreads();
  for (int t4 = tid; t4 < C0*NA/4; t4 += 128) {
    const float* kd = K0f + (size_t)t4*12;
    float4 k0 = *(const float4*)(kd);
    float4 k1 = *(const float4*)(kd + 4);
    float4 k2 = *(const float4*)(kd + 8);
    float m0=0.f, m1=0.f, m2=0.f, m3=0.f;   // relu then max => >= 0
    #pragma unroll
    for (int k = 0; k < KNN; ++k) {
      float dx = dk[k][0], dy = dk[k][1], dz = dk[k][2];
      m0 = fmaxf(m0, (dx*k0.x + dy*k0.y) + dz*k0.z);
      m1 = fmaxf(m1, (dx*k0.w + dy*k1.x) + dz*k1.y);
      m2 = fmaxf(m2, (dx*k1.z + dy*k1.w) + dz*k2.x);
      m3 = fmaxf(m3, (dx*k2.y + dy*k2.z) + dz*k2.w);
    }
    uint2 r; r.x = packb(m0, m1); r.y = packb(m2, m3);
    ((uint2*)fm0)[(size_t)bq*(C0*NA/4) + t4] = r;
    row[4*t4+0] = m0; row[4*t4+1] = m1; row[4*t4+2] = m2; row[4*t4+3] = m3;
  }
  __syncthreads();
  if (tid < C0) {
    float m = row[tid*NA];
    #pragma unroll
    for (int a = 1; a < NA; ++a) m = fmaxf(m, row[tid*NA + a]);
    out0[(size_t)bq*C0 + tid] = m;
  }
}

// ---------------- linear v7: MFMA bf16, B-frags cached in regs, N split across blocks ----
typedef __attribute__((ext_vector_type(8))) short bf16x8;
typedef __attribute__((ext_vector_type(4))) float f32x4;

DEV void store1(float* p, float v) { *p = v; }
DEV void store1(u16* p, float v) { *p = f2b(v); }

template<int CI, int CO, int PT, int SPLITN, typename TO>
__global__ __launch_bounds__(256) void eq_linear_mfma(
    const u16* __restrict__ in,
    const u16* __restrict__ wc_hi, const u16* __restrict__ wc_lo,
    const u16* __restrict__ ws_hi, const u16* __restrict__ ws_lo,
    const float* __restrict__ bias, TO* __restrict__ fc, u16* __restrict__ g) {
  constexpr int MR = 12*PT;          // M rows per block
  constexpr int TM = MR/16;          // M tiles
  constexpr int TN = CO/16;          // N tiles (total)
  constexpr int NTC = TN/SPLITN;     // N tiles this block (== 4 => 1 per wave)
  constexpr int KF = CI/32;          // K frags
  constexpr int RS = CI + 8;         // LDS row stride (u16); 2-way banks (free)
  __shared__ u16 As[MR*RS];
  int tid = threadIdx.x;
  int mat = blockIdx.x & 1;
  int rest = blockIdx.x >> 1;
  int sp = rest % SPLITN;
  int pt0 = (rest / SPLITN) * PT;
  constexpr int EU = PT*CI*12/2;
  const unsigned* inw = (const unsigned*)(in + (size_t)pt0*CI*12);
  for (int t = tid; t < EU; t += 256) {
    unsigned v = inw[t];
    int e = 2*t;
    int pt = e / (CI*12), r = e % (CI*12);
    int c = r / 12, a = r % 12;
    As[(a*PT + pt)*RS + c] = (u16)v;
    As[((a+1)*PT + pt)*RS + c] = (u16)(v >> 16);
  }
  __syncthreads();
  int wave = tid >> 6, lane = tid & 63;
  int lr = lane & 15;                // A row / B col / D col
  int lk = lane >> 4;                // k-group (8 elems each)
  const u16* Whi = mat ? ws_hi : wc_hi;
  const u16* Wlo = mat ? ws_lo : wc_lo;
  for (int ntl = wave; ntl < NTC; ntl += 4) {
    int nt = sp*NTC + ntl;
    int n = nt*16 + lr;
    bf16x8 bh[KF], bl[KF];
    #pragma unroll
    for (int kf = 0; kf < KF; ++kf) {
      bh[kf] = *(const bf16x8*)&Whi[(size_t)n*CI + kf*32 + lk*8];
      bl[kf] = *(const bf16x8*)&Wlo[(size_t)n*CI + kf*32 + lk*8];
    }
    float bv = (mat == 0) ? bias[n] : 0.f;
    #pragma unroll
    for (int mt = 0; mt < TM; ++mt) {
      f32x4 acc = {0.f, 0.f, 0.f, 0.f};
      #pragma unroll
      for (int kf = 0; kf < KF; ++kf) {
        bf16x8 af = *(const bf16x8*)&As[(mt*16 + lr)*RS + kf*32 + lk*8];
        acc = __builtin_amdgcn_mfma_f32_16x16x32_bf16(af, bh[kf], acc, 0, 0, 0);
        acc = __builtin_amdgcn_mfma_f32_16x16x32_bf16(af, bl[kf], acc, 0, 0, 0);
      }
      #pragma unroll
      for (int j = 0; j < 4; ++j) {
        int m = mt*16 + lk*4 + j;
        int a = m / PT, pt = m % PT;
        float v = acc[j] + bv;
        size_t oaddr = ((size_t)(pt0 + pt)*CO + n)*NA + a;
        if (mat == 0) store1(fc + oaddr, v);
        else          store1(g + oaddr, v);
      }
    }
  }
}

// ---------------- fsmax + fused BN partial stats (unroll 10, f4 th loads) ----------------
__global__ __launch_bounds__(256) void eq_fsmax(
    const u16* __restrict__ g, const float4* __restrict__ vf,
    const float* __restrict__ dirs, const int* __restrict__ idx,
    u16* __restrict__ out, float* __restrict__ part, int npts, int co) {
  int bq = blockIdx.x;
  int b = bq / npts;
  __shared__ float th[KNN*NA];
  __shared__ float dk[KNN][3];
  __shared__ int nb[KNN];
  __shared__ float sstat[2][C3];     // co <= 256
  int tid = threadIdx.x;
  if (tid < KNN) {
    int m = idx[(size_t)bq*KNN + tid];
    nb[tid] = m;
    float4 vq = vf[bq];
    float4 vm = vf[(size_t)b*npts + m];
    float dx = vm.x - vq.x, dy = vm.y - vq.y, dz = vm.z - vq.z;
    float nrm = sqrtf((dx*dx + dy*dy) + dz*dz) + 1e-8f;
    dk[tid][0] = dx/nrm; dk[tid][1] = dy/nrm; dk[tid][2] = dz/nrm;
  }
  sstat[0][tid] = 0.f; sstat[1][tid] = 0.f;
  __syncthreads();
  if (tid < KNN*NA) {
    int k = tid / NA, a = tid % NA;
    float s = (dk[k][0]*dirs[a*3] + dk[k][1]*dirs[a*3+1]) + dk[k][2]*dirs[a*3+2];
    th[tid] = fmaxf(s, 0.f);
  }
  __syncthreads();
  int quarter = co*NA/4;
  uint2* dst = (uint2*)(out + (size_t)bq*co*NA);
  const uint2* gb = (const uint2*)(g + (size_t)b*npts*co*NA);
  for (int t4 = tid; t4 < quarter; t4 += 256) {
    int a = (4*t4) % NA;          // 0, 4, or 8 — quad never straddles an o-row
    const float* tha = th + a;
    float m0=-3.0e38f, m1=-3.0e38f, m2=-3.0e38f, m3=-3.0e38f;
    #pragma unroll 10
    for (int k = 0; k < KNN; ++k) {
      uint2 pv = gb[(size_t)nb[k]*quarter + t4];
      float4 tv = *(const float4*)(tha + k*NA);   // 16B-aligned: a%4==0, 48|k*NA*4
      m0 = fmaxf(m0, tv.x*b2f((u16)(pv.x)));
      m1 = fmaxf(m1, tv.y*b2f((u16)(pv.x >> 16)));
      m2 = fmaxf(m2, tv.z*b2f((u16)(pv.y)));
      m3 = fmaxf(m3, tv.w*b2f((u16)(pv.y >> 16)));
    }
    uint2 d = dst[t4];
    float v0 = b2f((u16)d.x) + m0;
    float v1 = b2f((u16)(d.x >> 16)) + m1;
    float v2 = b2f((u16)d.y) + m2;
    float v3 = b2f((u16)(d.y >> 16)) + m3;
    uint2 r; r.x = packb(v0, v1); r.y = packb(v2, v3);
    dst[t4] = r;
    int ch = t4 / 3;              // NA/4 = 3 quads per channel
    atomicAdd(&sstat[0][ch], (v0 + v1) + (v2 + v3));
    atomicAdd(&sstat[1][ch], (v0*v0 + v1*v1) + (v2*v2 + v3*v3));
  }
  __syncthreads();
  if (tid < co) {
    float* pg = part + (size_t)(bq & (BNG-1))*2*co;
    atomicAdd(&pg[tid], sstat[0][tid]);
    atomicAdd(&pg[co + tid], sstat[1][tid]);
  }
}

// ---------------- layer4: fsmax + fea_of fused, channel-split, vectorized ----------------
template<int SPL>
__global__ __launch_bounds__(256) void eq_fsmax_fea(
    const u16* __restrict__ g, const float* __restrict__ fcin,
    const float4* __restrict__ vf, const float* __restrict__ dirs,
    const int* __restrict__ idx, float* __restrict__ outfea,
    int npts, int co) {
  constexpr int CHUNK = C4 / SPL;
  int part = blockIdx.x % SPL;
  int bq = blockIdx.x / SPL;
  int b = bq / npts;
  __shared__ float th[KNN*NA];
  __shared__ float dk[KNN][3];
  __shared__ int nb[KNN];
  __shared__ float row[CHUNK*NA];
  int tid = threadIdx.x;
  if (tid < KNN) {
    int m = idx[(size_t)bq*KNN + tid];
    nb[tid] = m;
    float4 vq = vf[bq];
    float4 vm = vf[(size_t)b*npts + m];
    float dx = vm.x - vq.x, dy = vm.y - vq.y, dz = vm.z - vq.z;
    float nrm = sqrtf((dx*dx + dy*dy) + dz*dz) + 1e-8f;
    dk[tid][0] = dx/nrm; dk[tid][1] = dy/nrm; dk[tid][2] = dz/nrm;
  }
  __syncthreads();
  if (tid < KNN*NA) {
    int k = tid / NA, a = tid % NA;
    float s = (dk[k][0]*dirs[a*3] + dk[k][1]*dirs[a*3+1]) + dk[k][2]*dirs[a*3+2];
    th[tid] = fmaxf(s, 0.f);
  }
  __syncthreads();
  int o0 = part * CHUNK;
  const float4* fcr = (const float4*)(fcin + ((size_t)bq*co + o0)*NA);
  const uint2* gb = (const uint2*)(g + (size_t)b*npts*co*NA + (size_t)o0*NA);
  int gquarter = co*NA/4;
  for (int t4 = tid; t4 < CHUNK*NA/4; t4 += 256) {
    int a = (4*t4) % NA;
    const float* tha = th + a;
    float m0=-3.0e38f, m1=-3.0e38f, m2=-3.0e38f, m3=-3.0e38f;
    #pragma unroll 10
    for (int k = 0; k < KNN; ++k) {
      uint2 pv = gb[(size_t)nb[k]*gquarter + t4];
      float4 tv = *(const float4*)(tha + k*NA);
      m0 = fmaxf(m0, tv.x*b2f((u16)(pv.x)));
      m1 = fmaxf(m1, tv.y*b2f((u16)(pv.x >> 16)));
      m2 = fmaxf(m2, tv.z*b2f((u16)(pv.y)));
      m3 = fmaxf(m3, tv.w*b2f((u16)(pv.y >> 16)));
    }
    float4 fc4 = fcr[t4];
    row[4*t4+0] = fc4.x + m0;
    row[4*t4+1] = fc4.y + m1;
    row[4*t4+2] = fc4.z + m2;
    row[4*t4+3] = fc4.w + m3;
  }
  __syncthreads();
  for (int o = tid; o < CHUNK; o += 256) {
    float m = row[o*NA];
    #pragma unroll
    for (int a = 1; a < NA; ++a) m = fmaxf(m, row[o*NA + a]);
    outfea[(size_t)bq*co + o0 + o] = m;
  }
}

// ---------------- normalize + relu (in place) + fea_of (folds BNG partials) ----------------
__global__ __launch_bounds__(256) void eq_bnrelu_fea(
    u16* __restrict__ fm, const float* __restrict__ part,
    const float* __restrict__ gamma, const float* __restrict__ beta,
    float* __restrict__ outfea, int npts, int co) {
  int bq = blockIdx.x;
  int tid = threadIdx.x;
  __shared__ float sc[C3], sh[C3];
  __shared__ float row[C3*NA];
  for (int o = tid; o < co; o += 256) {
    float s = 0.f, s2 = 0.f;
    for (int g = 0; g < BNG; ++g) {
      s  += part[(size_t)g*2*co + o];
      s2 += part[(size_t)g*2*co + co + o];
    }
    float cnt = (float)(Bz*npts*NA);
    float mean = s / cnt;
    float var = fmaxf(s2 / cnt - mean*mean, 0.f);
    float inv = 1.0f / sqrtf(var + 1e-5f);
    sc[o] = gamma[o] * inv;
    sh[o] = beta[o] - mean * gamma[o] * inv;
  }
  __syncthreads();
  uint2* p = (uint2*)(fm + (size_t)bq*co*NA);
  int quarter = co*NA/4;
  for (int t4 = tid; t4 < quarter; t4 += 256) {
    int o = (4*t4) / NA;            // quad never straddles o-row
    float s = sc[o], h = sh[o];
    uint2 pv = p[t4];
    float v0 = fmaxf(b2f((u16)pv.x)*s + h, 0.f);
    float v1 = fmaxf(b2f((u16)(pv.x >> 16))*s + h, 0.f);
    float v2 = fmaxf(b2f((u16)pv.y)*s + h, 0.f);
    float v3 = fmaxf(b2f((u16)(pv.y >> 16))*s + h, 0.f);
    uint2 r; r.x = packb(v0, v1); r.y = packb(v2, v3);
    p[t4] = r;
    row[4*t4+0] = v0; row[4*t4+1] = v1; row[4*t4+2] = v2; row[4*t4+3] = v3;
  }
  __syncthreads();
  for (int o = tid; o < co; o += 256) {
    float m = row[o*NA];
    #pragma unroll
    for (int a = 1; a < NA; ++a) m = fmaxf(m, row[o*NA + a]);
    outfea[(size_t)bq*co + o] = m;
  }
}

// ---------------- fused BN+relu+fea+pool (layers 1 & 3: fm post-BN has no other consumer) ----
__global__ __launch_bounds__(256) void eq_bnfea_pool(
    const u16* __restrict__ fm, const float* __restrict__ part,
    const float* __restrict__ gamma, const float* __restrict__ beta,
    const int* __restrict__ idx, float* __restrict__ outfea,
    u16* __restrict__ fmp, int npts, int co) {
  int bq = blockIdx.x;
  int b = bq / npts, q = bq % npts;
  int tid = threadIdx.x;
  __shared__ float sc[C3], sh[C3];
  __shared__ float row[C3*NA];
  __shared__ int nb[4];
  for (int o = tid; o < co; o += 256) {
    float s = 0.f, s2 = 0.f;
    for (int g = 0; g < BNG; ++g) {
      s  += part[(size_t)g*2*co + o];
      s2 += part[(size_t)g*2*co + co + o];
    }
    float cnt = (float)(Bz*npts*NA);
    float mean = s / cnt;
    float var = fmaxf(s2 / cnt - mean*mean, 0.f);
    float inv = 1.0f / sqrtf(var + 1e-5f);
    sc[o] = gamma[o] * inv;
    sh[o] = beta[o] - mean * gamma[o] * inv;
  }
  bool do_pool = ((q & 3) == 0);       // POOL_RATE = 4
  if (do_pool && tid < 4) nb[tid] = idx[(size_t)bq*KNN + tid];  // POOL_K = 4 nearest
  __syncthreads();
  int quarter = co*NA/4;
  const uint2* own = (const uint2*)(fm + (size_t)bq*co*NA);
  const uint2* base = (const uint2*)(fm + (size_t)b*npts*co*NA);
  uint2* dst = (uint2*)(fmp + ((size_t)b*(npts/4) + (q >> 2))*co*NA);
  for (int t4 = tid; t4 < quarter; t4 += 256) {
    int o = (4*t4) / NA;               // quad never straddles o-row
    float s = sc[o], h = sh[o];
    uint2 pv = own[t4];
    float v0 = fmaxf(b2f((u16)pv.x)*s + h, 0.f);
    float v1 = fmaxf(b2f((u16)(pv.x >> 16))*s + h, 0.f);
    float v2 = fmaxf(b2f((u16)pv.y)*s + h, 0.f);
    float v3 = fmaxf(b2f((u16)(pv.y >> 16))*s + h, 0.f);
    row[4*t4+0] = v0; row[4*t4+1] = v1; row[4*t4+2] = v2; row[4*t4+3] = v3;
    if (do_pool) {
      float m0=v0, m1=v1, m2=v2, m3=v3;
      #pragma unroll
      for (int kk = 0; kk < 4; ++kk) {
        uint2 w = base[(size_t)nb[kk]*quarter + t4];
        m0 = fmaxf(m0, fmaxf(b2f((u16)w.x)*s + h, 0.f));
        m1 = fmaxf(m1, fmaxf(b2f((u16)(w.x >> 16))*s + h, 0.f));
        m2 = fmaxf(m2, fmaxf(b2f((u16)w.y)*s + h, 0.f));
        m3 = fmaxf(m3, fmaxf(b2f((u16)(w.y >> 16))*s + h, 0.f));
      }
      uint2 r; r.x = packb(m0, m1); r.y = packb(m2, m3);
      dst[t4] = r;
    }
  }
  __syncthreads();
  for (int o = tid; o < co; o += 256) {
    float m = row[o*NA];
    #pragma unroll
    for (int a = 1; a < NA; ++a) m = fmaxf(m, row[o*NA + a]);
    outfea[(size_t)bq*co + o] = m;
  }
}

// ---------------- host orchestration ----------------
extern "C" void kernel_launch(void* const* d_in, const int* in_sizes, int n_in,
                              void* d_out, int out_size, void* d_ws, size_t ws_size,
                              hipStream_t stream) {
  float* ws = (float*)d_ws;
  float* out = (float*)d_out;
  u16* arena = (u16*)(ws + OFF_HALF);

  InPtrs ip;
  for (int i = 0; i < 24; ++i) ip.p[i] = d_in[i];

  float4* v0f = (float4*)(ws + OFF_V0F);
  float4* v1f = (float4*)(ws + OFF_V1F);
  float4* v2f = (float4*)(ws + OFF_V2F);
  int* idx0 = (int*)(ws + OFF_IDX0);
  int* idx1 = (int*)(ws + OFF_IDX1);
  int* idx2 = (int*)(ws + OFF_IDX2);
  u16* bufA = arena + HA;            // fm0 -> fm2
  u16* bufB = arena + HB;            // fm1 -> fm3 (RAW pre-BN)
  float* fc4f = (float*)(arena + HB);// layer4 fc carrier (fm3 dead by then)
  u16* bufG = arena + HG;            // g (Ws-transformed)
  u16* bufP = arena + HP;            // fmp1/fmp2 (upper half of G)
  u16* wch = arena + WTO;            // Wc split-bf16 transposed hi
  u16* wcl = wch + 174080;           // Wc lo
  u16* wsh = wcl + 174080;           // Ws hi
  u16* wsl = wsh + 174080;           // Ws lo
  float* partA = ws + OFF_PART;            // 32 x 2*C1
  float* partB = ws + OFF_PART + 4096;     // 32 x 2*C2
  float* partC = ws + OFF_PART + 12288;    // 32 x 2*C3
  const float* DIRS = ws + OFF_DIRS;

  // 0) convert all inputs; then split+transpose weights for MFMA
  {
    int total = Bz*N0 + 351312 + (int)PART_SZ;
    eq_convert_all<<<(total + 255)/256, 256, 0, stream>>>(ip, ws);
  }
  eq_wprep<<<(174080 + 255)/256, 256, 0, stream>>>(ws, wch, wcl, wsh, wsl);

  // 1) all 3 KNN levels in one dispatch
  eq_knn_all<<<Bz*N0/4 + Bz*N1/4 + Bz*N2/4, 256, 0, stream>>>(v0f, idx0, v1f, idx1, v2f, idx2);
  eq_conv_surface<<<Bz*N0, 128, 0, stream>>>(v0f, idx0, ws + OFF_K0F, bufA, out + OUT0);

  // 2) layer1: fm0(bufA,C0) -> fm1(bufB,C1) at N0; fused BN+fea+pool1 -> out1 + fmp1
  eq_linear_mfma<C0, C1, 8, 1, u16><<<(Bz*N0/8)*2*1, 256, 0, stream>>>(
      bufA, wch + 0, wcl + 0, wsh + 0, wsl + 0, ws + OFF_BC + 0, bufB, bufG);
  eq_fsmax<<<Bz*N0, 256, 0, stream>>>(bufG, v0f, DIRS + 0, idx0, bufB, partA, N0, C1);
  eq_bnfea_pool<<<Bz*N0, 256, 0, stream>>>(bufB, partA, ws + OFF_BN + 0, ws + OFF_BN + 64,
                                           idx0, out + OUT1, bufP, N0, C1);

  // 3) layer2: fmp1(bufP,C1) -> fm2(bufA,C2) at N1 (in-place BN kept: linear3 reads fm2)
  eq_linear_mfma<C1, C2, 8, 2, u16><<<(Bz*N1/8)*2*2, 256, 0, stream>>>(
      bufP, wch + 2048, wcl + 2048, wsh + 2048, wsl + 2048, ws + OFF_BC + 64, bufA, bufG);
  eq_fsmax<<<Bz*N1, 256, 0, stream>>>(bufG, v1f, DIRS + 36, idx1, bufA, partB, N1, C2);
  eq_bnrelu_fea<<<Bz*N1, 256, 0, stream>>>(bufA, partB, ws + OFF_BN + 128, ws + OFF_BN + 256,
                                           out + OUT2, N1, C2);

  // 4) layer3: fm2(bufA,C2) -> fm3(bufB,C3) at N1; fused BN+fea+pool2 -> out3 + fmp2
  eq_linear_mfma<C2, C3, 8, 4, u16><<<(Bz*N1/8)*2*4, 256, 0, stream>>>(
      bufA, wch + 10240, wcl + 10240, wsh + 10240, wsl + 10240, ws + OFF_BC + 192, bufB, bufG);
  eq_fsmax<<<Bz*N1, 256, 0, stream>>>(bufG, v1f, DIRS + 72, idx1, bufB, partC, N1, C3);
  eq_bnfea_pool<<<Bz*N1, 256, 0, stream>>>(bufB, partC, ws + OFF_BN + 384, ws + OFF_BN + 640,
                                           idx1, out + OUT3, bufP, N1, C3);

  // 5) layer4: fmp2(bufP,C3) -> fc4(f32) + g; fused fsmax+fea (4-way split) -> out4
  eq_linear_mfma<C3, C4, 4, 8, float><<<(Bz*N2/4)*2*8, 256, 0, stream>>>(
      bufP, wch + 43008, wcl + 43008, wsh + 43008, wsl + 43008, ws + OFF_BC + 448, fc4f, bufG);
  eq_fsmax_fea<4><<<Bz*N2*4, 256, 0, stream>>>(bufG, fc4f, v2f, DIRS + 108, idx2, out + OUT4, N2, C4);
}